// Round 10
// baseline (402.221 us; speedup 1.0000x reference)
//
#include <hip/hip_runtime.h>
#include <stdint.h>

// DSA sparse attention, MI355X. T=512 tok, H=128 heads, K=512 selected keys,
// C=576 (512 lora + 64 rope), S=8192 cache rows.
// Pipeline: prep (kv->bf16 + rope copy, SCALE folded), q_lat GEMM, scores GEMM,
// row softmax (writes A-fragment-swizzled P2), attn GEMM, out GEMM.
// MFMA tiling per m90/m92: A[m=lane&15][k=quad*8+j], B[n=lane&15][k=quad*8+j],
// D col=lane&15 row=quad*4+reg.
//
// R8->R9: counted-vmcnt pipelines: NEUTRAL -> scores not latency-bound.
// R9->R10/R11: attn v6 merged c-tiles (P2 read once, 8-wave block/token);
//         grid stride-512 siblings land same XCD (consecutive REGRESSED).
// R11->R12/R13: scores LDS-BW-bound (725cyc/slice == 64KB ds_read at 85B/cyc)
//         -> A-frags DIRECT from global qc; As staging deleted (LDS 48->24KB);
//         out_gemm same surgery. FAILED absmax 5.7e-3 (thr 2.6e-3).
// R13->R14: root cause: PROLOGUE RACE in scores. qc/kvb are __restrict__ and
//         ldsdma writes only LDS, so LLVM may legally reorder the af global
//         loads before the B0/B1 dma issues; then iter-0 vmcnt(6) retires
//         af0,af1 instead of B0 -> waves read Bs[0] before the gather lands.
//         Fix: asm ""::: "memory" fence + sched_barrier(0) pinning dma-issue
//         order in the prologue (and after the in-loop dma pair, cost-free).
// R14->R15: infra-failed round; resubmit unchanged after full vm-queue trace:
//         prologue vmcnt(6) retires exactly B0; steady-state compiler operand
//         waits retire B(ks+1) one iter early (manual wait = double-cover);
//         tail drains via final MFMA operand waits. Fix is complete.

#define SCALE 0.041666666666666664f  // (512+64)^-0.5

typedef __bf16 bf16x8 __attribute__((ext_vector_type(8)));
typedef float floatx4 __attribute__((ext_vector_type(4)));
typedef unsigned int uint32x2 __attribute__((ext_vector_type(2)));
typedef unsigned int uint32x4 __attribute__((ext_vector_type(4)));

static __device__ __forceinline__ unsigned short f2bf(float f) {
  unsigned int u = __builtin_bit_cast(unsigned int, f);
  u += 0x7FFF + ((u >> 16) & 1);  // RNE
  return (unsigned short)(u >> 16);
}
static __device__ __forceinline__ float bf2f(unsigned short h) {
  unsigned int u = ((unsigned int)h) << 16;
  return __builtin_bit_cast(float, u);
}
static __device__ __forceinline__ unsigned int pack2(float lo, float hi) {
  return (unsigned int)f2bf(lo) | ((unsigned int)f2bf(hi) << 16);
}
// async global->LDS, 16B per lane; LDS dest = wave base + lane*16 (m97 pattern)
static __device__ __forceinline__ void ldsdma16(const void* g, void* l) {
  __builtin_amdgcn_global_load_lds(
      (const __attribute__((address_space(1))) void*)g,
      (__attribute__((address_space(3))) void*)l, 16, 0, 0);
}
// IR-level memory fence + machine-sched fence: pins vm-op issue order
static __device__ __forceinline__ void issue_fence() {
  asm volatile("" ::: "memory");
  __builtin_amdgcn_sched_barrier(0);
}
// 32-bit LDS byte address for inline-asm DS ops
static __device__ __forceinline__ unsigned int lds_addr(const void* p) {
  return (unsigned int)(unsigned long long)(
      (__attribute__((address_space(3))) const void*)p);
}
// hardware transpose read: lane l gets column (l&15) of the 4x16 bf16 subtile
#define TR64(dst, addr, OFF) \
  asm volatile("ds_read_b64_tr_b16 %0, %1 offset:" OFF : "=v"(dst) : "v"(addr))

// stage 8 fp32 -> 8 bf16 into LDS (16B aligned)
static __device__ __forceinline__ void stage8_f32(const float* __restrict__ src,
                                                  unsigned short* dst) {
  const float4* s4 = reinterpret_cast<const float4*>(src);
  float4 v0 = s4[0], v1 = s4[1];
  uint4 o;
  o.x = pack2(v0.x, v0.y); o.y = pack2(v0.z, v0.w);
  o.z = pack2(v1.x, v1.y); o.w = pack2(v1.z, v1.w);
  *reinterpret_cast<uint4*>(dst) = o;
}

static __device__ __forceinline__ void mfma_4x4(const unsigned short* As,
                                                const unsigned short* Bs,
                                                int wm, int wn, int l15, int quad,
                                                floatx4 acc[4][4]) {
  bf16x8 af[4], bfr[4];
#pragma unroll
  for (int i = 0; i < 4; ++i)
    af[i] = *reinterpret_cast<const bf16x8*>(&As[(wm + i * 16 + l15) * 32 + quad * 8]);
#pragma unroll
  for (int j = 0; j < 4; ++j)
    bfr[j] = *reinterpret_cast<const bf16x8*>(&Bs[(wn + j * 16 + l15) * 32 + quad * 8]);
#pragma unroll
  for (int i = 0; i < 4; ++i)
#pragma unroll
    for (int j = 0; j < 4; ++j)
      acc[i][j] = __builtin_amdgcn_mfma_f32_16x16x32_bf16(af[i], bfr[j], acc[i][j], 0, 0, 0);
}

// ---------------- K0: kv_cache fp32 -> bf16  +  q_rope * SCALE -> q_concat ----------------
__global__ void prep(const float* __restrict__ kv, unsigned short* __restrict__ kvb,
                     const float* __restrict__ q, unsigned short* __restrict__ qc) {
  int b = blockIdx.x;
  if (b < 4608) {
    int i = b * 256 + threadIdx.x;  // per 4 elems, range sized exactly
    float4 v = reinterpret_cast<const float4*>(kv)[i];
    ushort4 o;
    o.x = f2bf(v.x); o.y = f2bf(v.y); o.z = f2bf(v.z); o.w = f2bf(v.w);
    reinterpret_cast<ushort4*>(kvb)[i] = o;
  } else {
    int i = (b - 4608) * 256 + threadIdx.x;  // 512*128*64 total
    int r = i & 63;
    int th = i >> 6;  // t*128 + h
    qc[(size_t)th * 576 + 512 + r] = f2bf(q[(size_t)th * 192 + 128 + r] * SCALE);
  }
}

// ---------------- K1: q_lat = per-head (T x 128) @ (512 x 128)^T, * SCALE ----------------
// grid (128, 16): x = h -> the 16 tile-blocks of one head are stride-128 apart
// (128%8==0: same XCD round-robin class).
__global__ __launch_bounds__(256) void qlat_gemm(const float* __restrict__ q,
                                                 const float* __restrict__ kb,
                                                 unsigned short* __restrict__ qc) {
  const int h = blockIdx.x;
  const int tm = (blockIdx.y & 3) * 128;   // token tile
  const int tn = (blockIdx.y >> 2) * 128;  // lora-dim tile
  __shared__ __align__(16) unsigned short As[128 * 32];
  __shared__ __align__(16) unsigned short Bs[128 * 32];
  const int tid = threadIdx.x;
  const int lane = tid & 63, wave = tid >> 6;
  const int wm = (wave & 1) * 64, wn = (wave >> 1) * 64;
  const int l15 = lane & 15, quad = lane >> 4;
  const int r0 = tid >> 2, cg = tid & 3;  // chunk row, col-group(8)
  const float* a0 = q + ((size_t)(tm + r0) * 128 + h) * 192 + cg * 8;
  const float* a1 = q + ((size_t)(tm + r0 + 64) * 128 + h) * 192 + cg * 8;
  const float* b0 = kb + ((size_t)h * 512 + tn + r0) * 128 + cg * 8;
  const float* b1 = b0 + (size_t)64 * 128;
  floatx4 acc[4][4] = {};
  for (int ks = 0; ks < 4; ++ks) {  // contraction 128 = 4*32
    stage8_f32(a0 + ks * 32, &As[tid * 8]);
    stage8_f32(a1 + ks * 32, &As[2048 + tid * 8]);
    stage8_f32(b0 + ks * 32, &Bs[tid * 8]);
    stage8_f32(b1 + ks * 32, &Bs[2048 + tid * 8]);
    __syncthreads();
    mfma_4x4(As, Bs, wm, wn, l15, quad, acc);
    __syncthreads();
  }
#pragma unroll
  for (int i = 0; i < 4; ++i) {
    const int row = wm + i * 16 + quad * 4;  // token-local
#pragma unroll
    for (int j = 0; j < 4; ++j) {
      const int col = wn + j * 16 + l15;  // lora-dim-local
#pragma unroll
      for (int r = 0; r < 4; ++r) {
        const int t = tm + row + r;
        qc[((size_t)t * 128 + h) * 576 + tn + col] = f2bf(acc[i][j][r] * SCALE);
      }
    }
  }
}

// ---------------- K2: scores (128h x 128key tile) = Qc @ KVsel^T ----------------
// grid (512, 4): x = t -> the 4 key-tile siblings sharing A(t) are 512 apart
// (512%8==0: same XCD). A-frags DIRECT from global qc (bf16, L2-resident);
// only B staged: depth-3 Bs (24KB). Issue order pinned by fences so the
// manual vmcnt(6) provably covers B(ks) at every iteration.
__global__ __launch_bounds__(256) void scores_gemm(const unsigned short* __restrict__ qc,
                                                   const unsigned short* __restrict__ kvb,
                                                   const int* __restrict__ topk,
                                                   unsigned short* __restrict__ P) {
  const int t = blockIdx.x;
  const int tn = blockIdx.y * 128;  // key tile
  __shared__ __align__(16) unsigned short Bs[3][128 * 32];
  const int tid = threadIdx.x;
  const int lane = tid & 63, wave = tid >> 6;
  const int wm = (wave & 1) * 64, wn = (wave >> 1) * 64;
  const int l15 = lane & 15, quad = lane >> 4;
  const int r0 = tid >> 2, cg = tid & 3;
  const int idx0 = topk[t * 512 + tn + r0];
  const int idx1 = topk[t * 512 + tn + r0 + 64];
  const unsigned short* b0 = kvb + (size_t)idx0 * 576 + cg * 8;
  const unsigned short* b1 = kvb + (size_t)idx1 * 576 + cg * 8;
  // A-direct base: qc[t][wm + i*16 + l15][ks*32 + quad*8]
  const unsigned short* aab = qc + ((size_t)t * 128 + wm + l15) * 576 + quad * 8;
  floatx4 acc[4][4] = {};
  // prologue: B(0), B(1) DMA first (oldest vm ops -- pinned by fence), A(0) regs
  ldsdma16(b0, &Bs[0][tid * 8]);
  ldsdma16(b1, &Bs[0][2048 + tid * 8]);
  ldsdma16(b0 + 32, &Bs[1][tid * 8]);
  ldsdma16(b1 + 32, &Bs[1][2048 + tid * 8]);
  issue_fence();  // af loads must NOT reorder before the dma issues (R13 race)
  bf16x8 af[4], an[4];
#pragma unroll
  for (int i = 0; i < 4; ++i)
    af[i] = *reinterpret_cast<const bf16x8*>(aab + (size_t)i * 16 * 576);
  int bi = 0, bn = 2;  // read buffer, prefetch buffer (=(ks+2)%3)
  for (int ks = 0; ks < 18; ++ks) {  // contraction 576 = 18*32
    asm volatile("s_waitcnt vmcnt(6)" ::: "memory");  // B(ks) landed (this wave)
    __builtin_amdgcn_s_barrier();                     // ... for ALL waves
    if (ks < 16) {
      ldsdma16(b0 + (ks + 2) * 32, &Bs[bn][tid * 8]);
      ldsdma16(b1 + (ks + 2) * 32, &Bs[bn][2048 + tid * 8]);
      issue_fence();  // dma issued before an loads: vm queue order == comments
    }
    if (ks < 17) {
#pragma unroll
      for (int i = 0; i < 4; ++i)
        an[i] = *reinterpret_cast<const bf16x8*>(
            aab + (ks + 1) * 32 + (size_t)i * 16 * 576);
    }
    bf16x8 bfr[4];
#pragma unroll
    for (int j = 0; j < 4; ++j)
      bfr[j] = *reinterpret_cast<const bf16x8*>(
          &Bs[bi][(wn + j * 16 + l15) * 32 + quad * 8]);
#pragma unroll
    for (int i = 0; i < 4; ++i)
#pragma unroll
      for (int j = 0; j < 4; ++j)
        acc[i][j] =
            __builtin_amdgcn_mfma_f32_16x16x32_bf16(af[i], bfr[j], acc[i][j], 0, 0, 0);
    __builtin_amdgcn_s_barrier();  // Bs[bi] reads done -> reusable next iters
#pragma unroll
    for (int i = 0; i < 4; ++i) af[i] = an[i];
    bi = bi == 2 ? 0 : bi + 1;
    bn = bn == 2 ? 0 : bn + 1;
  }
#pragma unroll
  for (int i = 0; i < 4; ++i) {
    const int row = wm + i * 16 + quad * 4;  // head
#pragma unroll
    for (int j = 0; j < 4; ++j) {
      const int col = tn + wn + j * 16 + l15;  // key
#pragma unroll
      for (int r = 0; r < 4; ++r)
        P[((size_t)t * 128 + row + r) * 512 + col] = f2bf(acc[i][j][r]);
    }
  }
}

// ---------------- K3: softmax rows of 512; writes P2 in A-fragment order ----------------
__global__ __launch_bounds__(256) void softmax_rows(const unsigned short* __restrict__ Pin,
                                                    unsigned short* __restrict__ P2) {
  const int row = blockIdx.x * 4 + (threadIdx.x >> 6);  // t*128 + h
  const int t = row >> 7, h = row & 127;
  const int lane = threadIdx.x & 63;
  const unsigned short* rp = Pin + (size_t)row * 512 + lane * 8;
  uint4 raw = *reinterpret_cast<const uint4*>(rp);
  unsigned int w[4] = {raw.x, raw.y, raw.z, raw.w};
  float f[8];
  float mx = -1e30f;
#pragma unroll
  for (int i = 0; i < 8; ++i) {
    f[i] = bf2f((unsigned short)((w[i >> 1] >> ((i & 1) * 16)) & 0xFFFF));
    mx = fmaxf(mx, f[i]);
  }
#pragma unroll
  for (int off = 32; off; off >>= 1) mx = fmaxf(mx, __shfl_xor(mx, off, 64));
  float s = 0.f;
#pragma unroll
  for (int i = 0; i < 8; ++i) { f[i] = __expf(f[i] - mx); s += f[i]; }
#pragma unroll
  for (int off = 32; off; off >>= 1) s += __shfl_xor(s, off, 64);
  const float inv = 1.0f / s;
  uint4 o;
  o.x = pack2(f[0] * inv, f[1] * inv);
  o.y = pack2(f[2] * inv, f[3] * inv);
  o.z = pack2(f[4] * inv, f[5] * inv);
  o.w = pack2(f[6] * inv, f[7] * inv);
  unsigned short* wp =
      P2 + (((size_t)t * 16 + (lane >> 2)) * 128 + h) * 32 + (lane & 3) * 8;
  *reinterpret_cast<uint4*>(wp) = o;
}

// ---------------- K4: attn_lat = P @ KVsel[:, :512], FULL 128h x 512c per block ----------------
// grid (512): one block per token, 512 threads / 8 waves (wr=wave>>2 head-half,
// wc=wave&3 c-quarter), acc 4x8 frags. P2 A-fragments read ONCE per t.
// St[ks tile] = 32 keys x 512 c staged subtiled for tr_read: elem (key,c) at
// byte ((key>>2)*32 + (c>>4))*128 + (key&3)*32 + (c&15)*2; DMA source
// pre-permuted so lane-linear LDS realizes it. Depth-3 (96KB), vmcnt(4)/iter.
__global__ __launch_bounds__(512) void attn_gemm(const unsigned short* __restrict__ P2,
                                                 const unsigned short* __restrict__ kvb,
                                                 const int* __restrict__ topk,
                                                 unsigned short* __restrict__ alat) {
  const int t = blockIdx.x;
  __shared__ __align__(16) unsigned short St[3][32 * 512];
  const int tid = threadIdx.x;
  const int lane = tid & 63, wave = tid >> 6;
  const int wm = (wave >> 2) * 64;   // head base (0/64)
  const int wc = wave & 3;           // c-quarter
  const int l15 = lane & 15, quad = lane >> 4;
  // DMA permutation: thread tid, dma d: key = d*8 + (tid>>8)*4 + ((tid>>1)&3),
  // c = ((tid>>3)&31)*16 + (tid&1)*8  (16B per thread per d; 4 d = 32KB tile)
  const int keyBase = (tid >> 8) * 4 + ((tid >> 1) & 3);
  const int cA = ((tid >> 3) & 31) * 16 + (tid & 1) * 8;
  const int* tkrow = topk + t * 512;
  // A-fragment base: P2[((t*16+ks)*128 + wm+i*16+l15)*32 + quad*8]
  const unsigned short* a_base =
      P2 + ((size_t)t * 16 * 128 + wm + l15) * 32 + quad * 8;
  // tr_read base: subtile (kq=2*quad+h01, ct=wc*8+j) at byte (kq*32+ct)*128;
  // lane addr = quad*8192 + wc*1024 + l15*8; offsets j*128 (+4096 for h01=1)
  const unsigned int tra0 = lds_addr(&St[0][0]) + quad * 8192 + wc * 1024 + l15 * 8;
  floatx4 acc[4][8] = {};
  bf16x8 a_cur[4], a_nxt[4];
  int ip0, ip1, ip2, ip3;  // gather indices for tile ks+2
  {
#pragma unroll
    for (int d = 0; d < 4; ++d) {
      const int k0 = tkrow[d * 8 + keyBase];
      ldsdma16(kvb + (size_t)k0 * 576 + cA, &St[0][d * 4096 + tid * 8]);
    }
#pragma unroll
    for (int i = 0; i < 4; ++i)
      a_cur[i] = *reinterpret_cast<const bf16x8*>(a_base + (size_t)i * 16 * 32);
    ip0 = tkrow[64 + 0 * 8 + keyBase];
    ip1 = tkrow[64 + 1 * 8 + keyBase];
    ip2 = tkrow[64 + 2 * 8 + keyBase];
    ip3 = tkrow[64 + 3 * 8 + keyBase];
    issue_fence();  // St[1] dma stays the YOUNGEST vm group
#pragma unroll
    for (int d = 0; d < 4; ++d) {
      const int k1 = tkrow[32 + d * 8 + keyBase];
      ldsdma16(kvb + (size_t)k1 * 576 + cA, &St[1][d * 4096 + tid * 8]);
    }
  }
  int sti = 0, stp = 2;  // read buffer, prefetch buffer (=(ks+2)%3)
  for (int ks = 0; ks < 16; ++ks) {
    // DMA(ks) is >=12 vm ops old; vmcnt(4) leaves only the newest tile's DMA
    // (issued last previous iter) in flight.
    asm volatile("s_waitcnt vmcnt(4)" ::: "memory");
    __builtin_amdgcn_s_barrier();  // St[sti] full for all waves; St[stp] free
    const unsigned int tra = tra0 + sti * 32768;
    uint32x2 rl0, rl1, rl2, rl3, rl4, rl5, rl6, rl7;
    uint32x2 rh0, rh1, rh2, rh3, rh4, rh5, rh6, rh7;
    TR64(rl0, tra, "0");    TR64(rh0, tra, "4096");
    TR64(rl1, tra, "128");  TR64(rh1, tra, "4224");
    TR64(rl2, tra, "256");  TR64(rh2, tra, "4352");
    TR64(rl3, tra, "384");  TR64(rh3, tra, "4480");
    TR64(rl4, tra, "512");  TR64(rh4, tra, "4608");
    TR64(rl5, tra, "640");  TR64(rh5, tra, "4736");
    TR64(rl6, tra, "768");  TR64(rh6, tra, "4864");
    TR64(rl7, tra, "896");  TR64(rh7, tra, "4992");
    if (ks < 15) {
#pragma unroll
      for (int i = 0; i < 4; ++i)
        a_nxt[i] = *reinterpret_cast<const bf16x8*>(
            a_base + ((size_t)(ks + 1) * 128 + i * 16) * 32);
    }
    if (ks < 14) {
      const int d0 = ip0, d1 = ip1, d2 = ip2, d3 = ip3;
      if (ks < 13) {
        ip0 = tkrow[(ks + 3) * 32 + 0 * 8 + keyBase];
        ip1 = tkrow[(ks + 3) * 32 + 1 * 8 + keyBase];
        ip2 = tkrow[(ks + 3) * 32 + 2 * 8 + keyBase];
        ip3 = tkrow[(ks + 3) * 32 + 3 * 8 + keyBase];
      }
      issue_fence();  // DMA issued last so it stays the youngest vm group
      ldsdma16(kvb + (size_t)d0 * 576 + cA, &St[stp][0 * 4096 + tid * 8]);
      ldsdma16(kvb + (size_t)d1 * 576 + cA, &St[stp][1 * 4096 + tid * 8]);
      ldsdma16(kvb + (size_t)d2 * 576 + cA, &St[stp][2 * 4096 + tid * 8]);
      ldsdma16(kvb + (size_t)d3 * 576 + cA, &St[stp][3 * 4096 + tid * 8]);
    }
    asm volatile("s_waitcnt lgkmcnt(0)");   // tr_reads complete
    __builtin_amdgcn_sched_barrier(0);      // rule #18: pin MFMAs after the wait
    bf16x8 bfr[8];
    {
      uint32x4 w;
      w.x = rl0.x; w.y = rl0.y; w.z = rh0.x; w.w = rh0.y; bfr[0] = __builtin_bit_cast(bf16x8, w);
      w.x = rl1.x; w.y = rl1.y; w.z = rh1.x; w.w = rh1.y; bfr[1] = __builtin_bit_cast(bf16x8, w);
      w.x = rl2.x; w.y = rl2.y; w.z = rh2.x; w.w = rh2.y; bfr[2] = __builtin_bit_cast(bf16x8, w);
      w.x = rl3.x; w.y = rl3.y; w.z = rh3.x; w.w = rh3.y; bfr[3] = __builtin_bit_cast(bf16x8, w);
      w.x = rl4.x; w.y = rl4.y; w.z = rh4.x; w.w = rh4.y; bfr[4] = __builtin_bit_cast(bf16x8, w);
      w.x = rl5.x; w.y = rl5.y; w.z = rh5.x; w.w = rh5.y; bfr[5] = __builtin_bit_cast(bf16x8, w);
      w.x = rl6.x; w.y = rl6.y; w.z = rh6.x; w.w = rh6.y; bfr[6] = __builtin_bit_cast(bf16x8, w);
      w.x = rl7.x; w.y = rl7.y; w.z = rh7.x; w.w = rh7.y; bfr[7] = __builtin_bit_cast(bf16x8, w);
    }
#pragma unroll
    for (int i = 0; i < 4; ++i)
#pragma unroll
      for (int j = 0; j < 8; ++j)
        acc[i][j] =
            __builtin_amdgcn_mfma_f32_16x16x32_bf16(a_cur[i], bfr[j], acc[i][j], 0, 0, 0);
#pragma unroll
    for (int i = 0; i < 4; ++i) a_cur[i] = a_nxt[i];
    sti = sti == 2 ? 0 : sti + 1;
    stp = stp == 2 ? 0 : stp + 1;
  }
  // write attn_lat in (H, T, 512) layout for K5's contiguous A reads
#pragma unroll
  for (int i = 0; i < 4; ++i) {
    const int row = wm + i * 16 + quad * 4;  // head
#pragma unroll
    for (int j = 0; j < 8; ++j) {
      const int col = wc * 128 + j * 16 + l15;  // c
#pragma unroll
      for (int r = 0; r < 4; ++r)
        alat[((size_t)(row + r) * 512 + t) * 512 + col] = f2bf(acc[i][j][r]);
    }
  }
}

// ---------------- K5: out (128t x 128v tile) = attn_lat[h] @ v_b[h]^T ----------------
// grid (128, 4): x = h -> token-tile siblings sharing B(h) are stride-128 apart
// (same XCD). A-frags DIRECT from global alat (bf16); only B (fp32 vb) staged.
// __syncthreads (full drain) -> no issue-order hazard here.
__global__ __launch_bounds__(256) void out_gemm(const unsigned short* __restrict__ alat,
                                                const float* __restrict__ vb,
                                                float* __restrict__ out) {
  const int h = blockIdx.x;
  const int tm = blockIdx.y * 128;  // token tile
  __shared__ __align__(16) unsigned short Bs[128 * 32];
  const int tid = threadIdx.x;
  const int lane = tid & 63, wave = tid >> 6;
  const int wm = (wave & 1) * 64, wn = (wave >> 1) * 64;
  const int l15 = lane & 15, quad = lane >> 4;
  const int r0 = tid >> 2, cg = tid & 3;
  // A-direct base: alat[h][tm + wm + i*16 + l15][ks*32 + quad*8]
  const unsigned short* aab =
      alat + ((size_t)h * 512 + tm + wm + l15) * 512 + quad * 8;
  const float* b0 = vb + ((size_t)h * 128 + r0) * 512 + cg * 8;
  const float* b1 = b0 + (size_t)64 * 512;
  floatx4 acc[4][4] = {};
  for (int ks = 0; ks < 16; ++ks) {  // contraction 512 = 16*32
    stage8_f32(b0 + ks * 32, &Bs[tid * 8]);
    stage8_f32(b1 + ks * 32, &Bs[2048 + tid * 8]);
    __syncthreads();
    bf16x8 af[4], bfr[4];
#pragma unroll
    for (int i = 0; i < 4; ++i)
      af[i] = *reinterpret_cast<const bf16x8*>(
          aab + ks * 32 + (size_t)i * 16 * 512);
#pragma unroll
    for (int j = 0; j < 4; ++j)
      bfr[j] = *reinterpret_cast<const bf16x8*>(
          &Bs[(wn + j * 16 + l15) * 32 + quad * 8]);
#pragma unroll
    for (int i = 0; i < 4; ++i)
#pragma unroll
      for (int j = 0; j < 4; ++j)
        acc[i][j] =
            __builtin_amdgcn_mfma_f32_16x16x32_bf16(af[i], bfr[j], acc[i][j], 0, 0, 0);
    __syncthreads();
  }
#pragma unroll
  for (int i = 0; i < 4; ++i) {
    const int row = wm + i * 16 + quad * 4;  // token-local
#pragma unroll
    for (int j = 0; j < 4; ++j) {
      const int col = wn + j * 16 + l15;  // v
#pragma unroll
      for (int r = 0; r < 4; ++r) {
        const int t = tm + row + r;
        out[((size_t)t * 128 + h) * 128 + col] = acc[i][j][r];
      }
    }
  }
}

extern "C" void kernel_launch(void* const* d_in, const int* in_sizes, int n_in,
                              void* d_out, int out_size, void* d_ws, size_t ws_size,
                              hipStream_t stream) {
  const float* q = (const float*)d_in[0];         // (512,128,192)
  const float* kv = (const float*)d_in[1];        // (8192,576)
  const int* topk = (const int*)d_in[2];          // (512,512)
  const float* kb = (const float*)d_in[3];        // (128,512,128)
  const float* vb = (const float*)d_in[4];        // (128,128,512)
  float* out = (float*)d_out;                     // (512,128,128)

  char* ws = (char*)d_ws;
  unsigned short* kvb = (unsigned short*)ws;                       // 9,437,184 B
  unsigned short* qc = (unsigned short*)(ws + 9437184);            // 75,497,472 B
  unsigned short* P = (unsigned short*)(ws + 9437184 + 75497472);  // 67,108,864 B
  // lifetime reuse (no growth, 152 MB total):
  unsigned short* P2 = qc;    // qc dead after scores_gemm; softmax writes here
  unsigned short* alat = P;   // P dead after softmax; attn writes here

  prep<<<dim3(20992), dim3(256), 0, stream>>>(kv, kvb, q, qc);
  qlat_gemm<<<dim3(128, 16), dim3(256), 0, stream>>>(q, kb, qc);
  scores_gemm<<<dim3(512, 4), dim3(256), 0, stream>>>(qc, kvb, topk, P);
  softmax_rows<<<dim3(16384), dim3(256), 0, stream>>>(P, P2);
  attn_gemm<<<dim3(512), dim3(512), 0, stream>>>(P2, kvb, topk, alat);
  out_gemm<<<dim3(128, 4), dim3(256), 0, stream>>>(alat, vb, out);
}

// Round 11
// 384.569 us; speedup vs baseline: 1.0459x; 1.0459x over previous
//
#include <hip/hip_runtime.h>
#include <stdint.h>

// DSA sparse attention, MI355X. T=512 tok, H=128 heads, K=512 selected keys,
// C=576 (512 lora + 64 rope), S=8192 cache rows.
// Pipeline: prep (kv->bf16 + rope copy, SCALE folded), q_lat GEMM, scores GEMM,
// row softmax (writes A-fragment-swizzled P2), attn GEMM, out GEMM.
// MFMA tiling per m90/m92: A[m=lane&15][k=quad*8+j], B[n=lane&15][k=quad*8+j],
// D col=lane&15 row=quad*4+reg.
//
// R9->R10/R11: attn v6 merged c-tiles (P2 read once, 8-wave block/token);
//         stride-512 grid siblings land same XCD.
// R11->R12/R13/R14/R15: scores/out A-frags direct from global. R13 FAILED
//         (prologue vm-queue race; fixed with issue_fence in R14/R15).
//         R15 passed but REGRESSED: scores 87->108us, FETCH 218->267MB,
//         MfmaUtil 14%. Diagnosis: A-direct loads UNCOALESCED -- qc row
//         stride 1152B means a wave's 64x16B requests touch ~64 cache lines
//         (8x over-fetch). attn's A-direct worked because softmax wrote P2 in
//         FRAGMENT order (permuted-contiguous 1KB per wave-load).
// R15->R16: fragment-swizzle the producer layouts (address-only change):
//         qc2[((t*18+ks)*128+h)*32+kk] written by qlat epilogue + prep rope;
//         scores A-load = aab + ks*4096 + i*512 (wave-contiguous 1KB).
//         alat2[((h*16+ks)*512+t)*32+kk] written by attn epilogue; out A-load
//         likewise contiguous. Keeps R15's verified fenced depth-3 B pipeline
//         (24KB LDS) in scores; same sync structure everywhere.

#define SCALE 0.041666666666666664f  // (512+64)^-0.5

typedef __bf16 bf16x8 __attribute__((ext_vector_type(8)));
typedef float floatx4 __attribute__((ext_vector_type(4)));
typedef unsigned int uint32x2 __attribute__((ext_vector_type(2)));
typedef unsigned int uint32x4 __attribute__((ext_vector_type(4)));

static __device__ __forceinline__ unsigned short f2bf(float f) {
  unsigned int u = __builtin_bit_cast(unsigned int, f);
  u += 0x7FFF + ((u >> 16) & 1);  // RNE
  return (unsigned short)(u >> 16);
}
static __device__ __forceinline__ float bf2f(unsigned short h) {
  unsigned int u = ((unsigned int)h) << 16;
  return __builtin_bit_cast(float, u);
}
static __device__ __forceinline__ unsigned int pack2(float lo, float hi) {
  return (unsigned int)f2bf(lo) | ((unsigned int)f2bf(hi) << 16);
}
// async global->LDS, 16B per lane; LDS dest = wave base + lane*16 (m97 pattern)
static __device__ __forceinline__ void ldsdma16(const void* g, void* l) {
  __builtin_amdgcn_global_load_lds(
      (const __attribute__((address_space(1))) void*)g,
      (__attribute__((address_space(3))) void*)l, 16, 0, 0);
}
// IR-level memory fence + machine-sched fence: pins vm-op issue order
static __device__ __forceinline__ void issue_fence() {
  asm volatile("" ::: "memory");
  __builtin_amdgcn_sched_barrier(0);
}
// 32-bit LDS byte address for inline-asm DS ops
static __device__ __forceinline__ unsigned int lds_addr(const void* p) {
  return (unsigned int)(unsigned long long)(
      (__attribute__((address_space(3))) const void*)p);
}
// hardware transpose read: lane l gets column (l&15) of the 4x16 bf16 subtile
#define TR64(dst, addr, OFF) \
  asm volatile("ds_read_b64_tr_b16 %0, %1 offset:" OFF : "=v"(dst) : "v"(addr))

// stage 8 fp32 -> 8 bf16 into LDS (16B aligned)
static __device__ __forceinline__ void stage8_f32(const float* __restrict__ src,
                                                  unsigned short* dst) {
  const float4* s4 = reinterpret_cast<const float4*>(src);
  float4 v0 = s4[0], v1 = s4[1];
  uint4 o;
  o.x = pack2(v0.x, v0.y); o.y = pack2(v0.z, v0.w);
  o.z = pack2(v1.x, v1.y); o.w = pack2(v1.z, v1.w);
  *reinterpret_cast<uint4*>(dst) = o;
}

static __device__ __forceinline__ void mfma_4x4(const unsigned short* As,
                                                const unsigned short* Bs,
                                                int wm, int wn, int l15, int quad,
                                                floatx4 acc[4][4]) {
  bf16x8 af[4], bfr[4];
#pragma unroll
  for (int i = 0; i < 4; ++i)
    af[i] = *reinterpret_cast<const bf16x8*>(&As[(wm + i * 16 + l15) * 32 + quad * 8]);
#pragma unroll
  for (int j = 0; j < 4; ++j)
    bfr[j] = *reinterpret_cast<const bf16x8*>(&Bs[(wn + j * 16 + l15) * 32 + quad * 8]);
#pragma unroll
  for (int i = 0; i < 4; ++i)
#pragma unroll
    for (int j = 0; j < 4; ++j)
      acc[i][j] = __builtin_amdgcn_mfma_f32_16x16x32_bf16(af[i], bfr[j], acc[i][j], 0, 0, 0);
}

// ---------------- K0: kv_cache fp32 -> bf16  +  q_rope * SCALE -> qc2 ----------------
// qc2 layout (A-fragment order for scores): elem (t, h, c) at
// ((t*18 + (c>>5))*128 + h)*32 + (c&31). rope covers c in [512,576) -> ks 16,17.
__global__ void prep(const float* __restrict__ kv, unsigned short* __restrict__ kvb,
                     const float* __restrict__ q, unsigned short* __restrict__ qc2) {
  int b = blockIdx.x;
  if (b < 4608) {
    int i = b * 256 + threadIdx.x;  // per 4 elems, range sized exactly
    float4 v = reinterpret_cast<const float4*>(kv)[i];
    ushort4 o;
    o.x = f2bf(v.x); o.y = f2bf(v.y); o.z = f2bf(v.z); o.w = f2bf(v.w);
    reinterpret_cast<ushort4*>(kvb)[i] = o;
  } else {
    int i = (b - 4608) * 256 + threadIdx.x;  // 512*128*64 total
    int r = i & 63;
    int th = i >> 6;  // t*128 + h
    int t = th >> 7, h = th & 127;
    qc2[(((size_t)t * 18 + 16 + (r >> 5)) * 128 + h) * 32 + (r & 31)] =
        f2bf(q[(size_t)th * 192 + 128 + r] * SCALE);
  }
}

// ---------------- K1: q_lat = per-head (T x 128) @ (512 x 128)^T, * SCALE ----------------
// grid (128, 16): x = h -> the 16 tile-blocks of one head are stride-128 apart
// (128%8==0: same XCD round-robin class). Epilogue writes qc2 fragment order.
__global__ __launch_bounds__(256) void qlat_gemm(const float* __restrict__ q,
                                                 const float* __restrict__ kb,
                                                 unsigned short* __restrict__ qc2) {
  const int h = blockIdx.x;
  const int tm = (blockIdx.y & 3) * 128;   // token tile
  const int tn = (blockIdx.y >> 2) * 128;  // lora-dim tile
  __shared__ __align__(16) unsigned short As[128 * 32];
  __shared__ __align__(16) unsigned short Bs[128 * 32];
  const int tid = threadIdx.x;
  const int lane = tid & 63, wave = tid >> 6;
  const int wm = (wave & 1) * 64, wn = (wave >> 1) * 64;
  const int l15 = lane & 15, quad = lane >> 4;
  const int r0 = tid >> 2, cg = tid & 3;  // chunk row, col-group(8)
  const float* a0 = q + ((size_t)(tm + r0) * 128 + h) * 192 + cg * 8;
  const float* a1 = q + ((size_t)(tm + r0 + 64) * 128 + h) * 192 + cg * 8;
  const float* b0 = kb + ((size_t)h * 512 + tn + r0) * 128 + cg * 8;
  const float* b1 = b0 + (size_t)64 * 128;
  floatx4 acc[4][4] = {};
  for (int ks = 0; ks < 4; ++ks) {  // contraction 128 = 4*32
    stage8_f32(a0 + ks * 32, &As[tid * 8]);
    stage8_f32(a1 + ks * 32, &As[2048 + tid * 8]);
    stage8_f32(b0 + ks * 32, &Bs[tid * 8]);
    stage8_f32(b1 + ks * 32, &Bs[2048 + tid * 8]);
    __syncthreads();
    mfma_4x4(As, Bs, wm, wn, l15, quad, acc);
    __syncthreads();
  }
#pragma unroll
  for (int i = 0; i < 4; ++i) {
    const int row = wm + i * 16 + quad * 4;  // token-local
#pragma unroll
    for (int j = 0; j < 4; ++j) {
      const int c = tn + wn + j * 16 + l15;  // lora-dim (global)
      const int ks2 = c >> 5, kk = c & 31;
#pragma unroll
      for (int r = 0; r < 4; ++r) {
        const int t = tm + row + r;
        qc2[(((size_t)t * 18 + ks2) * 128 + h) * 32 + kk] = f2bf(acc[i][j][r] * SCALE);
      }
    }
  }
}

// ---------------- K2: scores (128h x 128key tile) = Qc2 @ KVsel^T ----------------
// grid (512, 4): x = t -> the 4 key-tile siblings sharing A(t) are 512 apart
// (512%8==0: same XCD). A-frags DIRECT from qc2 (fragment order: each wave's
// load is a permuted-contiguous 1KB block -> fully coalesced). Only B staged:
// depth-3 Bs (24KB), fenced issue order, counted vmcnt(6).
__global__ __launch_bounds__(256) void scores_gemm(const unsigned short* __restrict__ qc2,
                                                   const unsigned short* __restrict__ kvb,
                                                   const int* __restrict__ topk,
                                                   unsigned short* __restrict__ P) {
  const int t = blockIdx.x;
  const int tn = blockIdx.y * 128;  // key tile
  __shared__ __align__(16) unsigned short Bs[3][128 * 32];
  const int tid = threadIdx.x;
  const int lane = tid & 63, wave = tid >> 6;
  const int wm = (wave & 1) * 64, wn = (wave >> 1) * 64;
  const int l15 = lane & 15, quad = lane >> 4;
  const int r0 = tid >> 2, cg = tid & 3;
  const int idx0 = topk[t * 512 + tn + r0];
  const int idx1 = topk[t * 512 + tn + r0 + 64];
  const unsigned short* b0 = kvb + (size_t)idx0 * 576 + cg * 8;
  const unsigned short* b1 = kvb + (size_t)idx1 * 576 + cg * 8;
  // A-frag base in qc2: ((t*18+ks)*128 + wm+i*16+l15)*32 + quad*8
  //                   = aab + ks*4096 + i*512
  const unsigned short* aab =
      qc2 + ((size_t)t * 2304 + wm + l15) * 32 + quad * 8;
  floatx4 acc[4][4] = {};
  // prologue: B(0), B(1) DMA first (oldest vm ops -- pinned by fence), A(0) regs
  ldsdma16(b0, &Bs[0][tid * 8]);
  ldsdma16(b1, &Bs[0][2048 + tid * 8]);
  ldsdma16(b0 + 32, &Bs[1][tid * 8]);
  ldsdma16(b1 + 32, &Bs[1][2048 + tid * 8]);
  issue_fence();  // af loads must NOT reorder before the dma issues (R13 race)
  bf16x8 af[4], an[4];
#pragma unroll
  for (int i = 0; i < 4; ++i)
    af[i] = *reinterpret_cast<const bf16x8*>(aab + i * 512);
  int bi = 0, bn = 2;  // read buffer, prefetch buffer (=(ks+2)%3)
  for (int ks = 0; ks < 18; ++ks) {  // contraction 576 = 18*32
    asm volatile("s_waitcnt vmcnt(6)" ::: "memory");  // B(ks) landed (this wave)
    __builtin_amdgcn_s_barrier();                     // ... for ALL waves
    if (ks < 16) {
      ldsdma16(b0 + (ks + 2) * 32, &Bs[bn][tid * 8]);
      ldsdma16(b1 + (ks + 2) * 32, &Bs[bn][2048 + tid * 8]);
      issue_fence();  // dma issued before an loads: vm queue order == comments
    }
    if (ks < 17) {
#pragma unroll
      for (int i = 0; i < 4; ++i)
        an[i] = *reinterpret_cast<const bf16x8*>(
            aab + (size_t)(ks + 1) * 4096 + i * 512);
    }
    bf16x8 bfr[4];
#pragma unroll
    for (int j = 0; j < 4; ++j)
      bfr[j] = *reinterpret_cast<const bf16x8*>(
          &Bs[bi][(wn + j * 16 + l15) * 32 + quad * 8]);
#pragma unroll
    for (int i = 0; i < 4; ++i)
#pragma unroll
      for (int j = 0; j < 4; ++j)
        acc[i][j] =
            __builtin_amdgcn_mfma_f32_16x16x32_bf16(af[i], bfr[j], acc[i][j], 0, 0, 0);
    __builtin_amdgcn_s_barrier();  // Bs[bi] reads done -> reusable next iters
#pragma unroll
    for (int i = 0; i < 4; ++i) af[i] = an[i];
    bi = bi == 2 ? 0 : bi + 1;
    bn = bn == 2 ? 0 : bn + 1;
  }
#pragma unroll
  for (int i = 0; i < 4; ++i) {
    const int row = wm + i * 16 + quad * 4;  // head
#pragma unroll
    for (int j = 0; j < 4; ++j) {
      const int col = tn + wn + j * 16 + l15;  // key
#pragma unroll
      for (int r = 0; r < 4; ++r)
        P[((size_t)t * 128 + row + r) * 512 + col] = f2bf(acc[i][j][r]);
    }
  }
}

// ---------------- K3: softmax rows of 512; writes P2 in A-fragment order ----------------
__global__ __launch_bounds__(256) void softmax_rows(const unsigned short* __restrict__ Pin,
                                                    unsigned short* __restrict__ P2) {
  const int row = blockIdx.x * 4 + (threadIdx.x >> 6);  // t*128 + h
  const int t = row >> 7, h = row & 127;
  const int lane = threadIdx.x & 63;
  const unsigned short* rp = Pin + (size_t)row * 512 + lane * 8;
  uint4 raw = *reinterpret_cast<const uint4*>(rp);
  unsigned int w[4] = {raw.x, raw.y, raw.z, raw.w};
  float f[8];
  float mx = -1e30f;
#pragma unroll
  for (int i = 0; i < 8; ++i) {
    f[i] = bf2f((unsigned short)((w[i >> 1] >> ((i & 1) * 16)) & 0xFFFF));
    mx = fmaxf(mx, f[i]);
  }
#pragma unroll
  for (int off = 32; off; off >>= 1) mx = fmaxf(mx, __shfl_xor(mx, off, 64));
  float s = 0.f;
#pragma unroll
  for (int i = 0; i < 8; ++i) { f[i] = __expf(f[i] - mx); s += f[i]; }
#pragma unroll
  for (int off = 32; off; off >>= 1) s += __shfl_xor(s, off, 64);
  const float inv = 1.0f / s;
  uint4 o;
  o.x = pack2(f[0] * inv, f[1] * inv);
  o.y = pack2(f[2] * inv, f[3] * inv);
  o.z = pack2(f[4] * inv, f[5] * inv);
  o.w = pack2(f[6] * inv, f[7] * inv);
  unsigned short* wp =
      P2 + (((size_t)t * 16 + (lane >> 2)) * 128 + h) * 32 + (lane & 3) * 8;
  *reinterpret_cast<uint4*>(wp) = o;
}

// ---------------- K4: attn_lat = P @ KVsel[:, :512], FULL 128h x 512c per block ----------------
// grid (512): one block per token, 512 threads / 8 waves (wr=wave>>2 head-half,
// wc=wave&3 c-quarter), acc 4x8 frags. P2 A-fragments read ONCE per t.
// St[ks tile] = 32 keys x 512 c staged subtiled for tr_read; DMA source
// pre-permuted so lane-linear LDS realizes it. Depth-3 (96KB), vmcnt(4)/iter.
// Epilogue writes alat2 in out_gemm's A-fragment order.
__global__ __launch_bounds__(512) void attn_gemm(const unsigned short* __restrict__ P2,
                                                 const unsigned short* __restrict__ kvb,
                                                 const int* __restrict__ topk,
                                                 unsigned short* __restrict__ alat2) {
  const int t = blockIdx.x;
  __shared__ __align__(16) unsigned short St[3][32 * 512];
  const int tid = threadIdx.x;
  const int lane = tid & 63, wave = tid >> 6;
  const int wm = (wave >> 2) * 64;   // head base (0/64)
  const int wc = wave & 3;           // c-quarter
  const int l15 = lane & 15, quad = lane >> 4;
  // DMA permutation: thread tid, dma d: key = d*8 + (tid>>8)*4 + ((tid>>1)&3),
  // c = ((tid>>3)&31)*16 + (tid&1)*8  (16B per thread per d; 4 d = 32KB tile)
  const int keyBase = (tid >> 8) * 4 + ((tid >> 1) & 3);
  const int cA = ((tid >> 3) & 31) * 16 + (tid & 1) * 8;
  const int* tkrow = topk + t * 512;
  // A-fragment base: P2[((t*16+ks)*128 + wm+i*16+l15)*32 + quad*8]
  const unsigned short* a_base =
      P2 + ((size_t)t * 16 * 128 + wm + l15) * 32 + quad * 8;
  // tr_read base: subtile (kq=2*quad+h01, ct=wc*8+j) at byte (kq*32+ct)*128;
  // lane addr = quad*8192 + wc*1024 + l15*8; offsets j*128 (+4096 for h01=1)
  const unsigned int tra0 = lds_addr(&St[0][0]) + quad * 8192 + wc * 1024 + l15 * 8;
  floatx4 acc[4][8] = {};
  bf16x8 a_cur[4], a_nxt[4];
  int ip0, ip1, ip2, ip3;  // gather indices for tile ks+2
  {
#pragma unroll
    for (int d = 0; d < 4; ++d) {
      const int k0 = tkrow[d * 8 + keyBase];
      ldsdma16(kvb + (size_t)k0 * 576 + cA, &St[0][d * 4096 + tid * 8]);
    }
#pragma unroll
    for (int i = 0; i < 4; ++i)
      a_cur[i] = *reinterpret_cast<const bf16x8*>(a_base + (size_t)i * 16 * 32);
    ip0 = tkrow[64 + 0 * 8 + keyBase];
    ip1 = tkrow[64 + 1 * 8 + keyBase];
    ip2 = tkrow[64 + 2 * 8 + keyBase];
    ip3 = tkrow[64 + 3 * 8 + keyBase];
    issue_fence();  // St[1] dma stays the YOUNGEST vm group
#pragma unroll
    for (int d = 0; d < 4; ++d) {
      const int k1 = tkrow[32 + d * 8 + keyBase];
      ldsdma16(kvb + (size_t)k1 * 576 + cA, &St[1][d * 4096 + tid * 8]);
    }
  }
  int sti = 0, stp = 2;  // read buffer, prefetch buffer (=(ks+2)%3)
  for (int ks = 0; ks < 16; ++ks) {
    // DMA(ks) is >=12 vm ops old; vmcnt(4) leaves only the newest tile's DMA
    // (issued last previous iter) in flight.
    asm volatile("s_waitcnt vmcnt(4)" ::: "memory");
    __builtin_amdgcn_s_barrier();  // St[sti] full for all waves; St[stp] free
    const unsigned int tra = tra0 + sti * 32768;
    uint32x2 rl0, rl1, rl2, rl3, rl4, rl5, rl6, rl7;
    uint32x2 rh0, rh1, rh2, rh3, rh4, rh5, rh6, rh7;
    TR64(rl0, tra, "0");    TR64(rh0, tra, "4096");
    TR64(rl1, tra, "128");  TR64(rh1, tra, "4224");
    TR64(rl2, tra, "256");  TR64(rh2, tra, "4352");
    TR64(rl3, tra, "384");  TR64(rh3, tra, "4480");
    TR64(rl4, tra, "512");  TR64(rh4, tra, "4608");
    TR64(rl5, tra, "640");  TR64(rh5, tra, "4736");
    TR64(rl6, tra, "768");  TR64(rh6, tra, "4864");
    TR64(rl7, tra, "896");  TR64(rh7, tra, "4992");
    if (ks < 15) {
#pragma unroll
      for (int i = 0; i < 4; ++i)
        a_nxt[i] = *reinterpret_cast<const bf16x8*>(
            a_base + ((size_t)(ks + 1) * 128 + i * 16) * 32);
    }
    if (ks < 14) {
      const int d0 = ip0, d1 = ip1, d2 = ip2, d3 = ip3;
      if (ks < 13) {
        ip0 = tkrow[(ks + 3) * 32 + 0 * 8 + keyBase];
        ip1 = tkrow[(ks + 3) * 32 + 1 * 8 + keyBase];
        ip2 = tkrow[(ks + 3) * 32 + 2 * 8 + keyBase];
        ip3 = tkrow[(ks + 3) * 32 + 3 * 8 + keyBase];
      }
      issue_fence();  // DMA issued last so it stays the youngest vm group
      ldsdma16(kvb + (size_t)d0 * 576 + cA, &St[stp][0 * 4096 + tid * 8]);
      ldsdma16(kvb + (size_t)d1 * 576 + cA, &St[stp][1 * 4096 + tid * 8]);
      ldsdma16(kvb + (size_t)d2 * 576 + cA, &St[stp][2 * 4096 + tid * 8]);
      ldsdma16(kvb + (size_t)d3 * 576 + cA, &St[stp][3 * 4096 + tid * 8]);
    }
    asm volatile("s_waitcnt lgkmcnt(0)");   // tr_reads complete
    __builtin_amdgcn_sched_barrier(0);      // rule #18: pin MFMAs after the wait
    bf16x8 bfr[8];
    {
      uint32x4 w;
      w.x = rl0.x; w.y = rl0.y; w.z = rh0.x; w.w = rh0.y; bfr[0] = __builtin_bit_cast(bf16x8, w);
      w.x = rl1.x; w.y = rl1.y; w.z = rh1.x; w.w = rh1.y; bfr[1] = __builtin_bit_cast(bf16x8, w);
      w.x = rl2.x; w.y = rl2.y; w.z = rh2.x; w.w = rh2.y; bfr[2] = __builtin_bit_cast(bf16x8, w);
      w.x = rl3.x; w.y = rl3.y; w.z = rh3.x; w.w = rh3.y; bfr[3] = __builtin_bit_cast(bf16x8, w);
      w.x = rl4.x; w.y = rl4.y; w.z = rh4.x; w.w = rh4.y; bfr[4] = __builtin_bit_cast(bf16x8, w);
      w.x = rl5.x; w.y = rl5.y; w.z = rh5.x; w.w = rh5.y; bfr[5] = __builtin_bit_cast(bf16x8, w);
      w.x = rl6.x; w.y = rl6.y; w.z = rh6.x; w.w = rh6.y; bfr[6] = __builtin_bit_cast(bf16x8, w);
      w.x = rl7.x; w.y = rl7.y; w.z = rh7.x; w.w = rh7.y; bfr[7] = __builtin_bit_cast(bf16x8, w);
    }
#pragma unroll
    for (int i = 0; i < 4; ++i)
#pragma unroll
      for (int j = 0; j < 8; ++j)
        acc[i][j] =
            __builtin_amdgcn_mfma_f32_16x16x32_bf16(a_cur[i], bfr[j], acc[i][j], 0, 0, 0);
#pragma unroll
    for (int i = 0; i < 4; ++i) a_cur[i] = a_nxt[i];
    sti = sti == 2 ? 0 : sti + 1;
    stp = stp == 2 ? 0 : stp + 1;
  }
  // write alat2 in out_gemm's A-fragment order:
  // elem (h=row+r, t, c) at ((h*16 + (c>>5))*512 + t)*32 + (c&31)
#pragma unroll
  for (int i = 0; i < 4; ++i) {
    const int row = wm + i * 16 + quad * 4;  // head
#pragma unroll
    for (int j = 0; j < 8; ++j) {
      const int c = wc * 128 + j * 16 + l15;  // c
      const int ks2 = c >> 5, kk = c & 31;
#pragma unroll
      for (int r = 0; r < 4; ++r)
        alat2[(((size_t)(row + r) * 16 + ks2) * 512 + t) * 32 + kk] =
            f2bf(acc[i][j][r]);
    }
  }
}

// ---------------- K5: out (128t x 128v tile) = attn_lat[h] @ v_b[h]^T ----------------
// grid (128, 4): x = h -> token-tile siblings sharing B(h) are stride-128 apart
// (same XCD). A-frags DIRECT from alat2 (fragment order -> coalesced);
// only B (fp32 vb) staged. __syncthreads (full drain) -> no ordering hazard.
__global__ __launch_bounds__(256) void out_gemm(const unsigned short* __restrict__ alat2,
                                                const float* __restrict__ vb,
                                                float* __restrict__ out) {
  const int h = blockIdx.x;
  const int tm = blockIdx.y * 128;  // token tile
  __shared__ __align__(16) unsigned short Bs[128 * 32];
  const int tid = threadIdx.x;
  const int lane = tid & 63, wave = tid >> 6;
  const int wm = (wave & 1) * 64, wn = (wave >> 1) * 64;
  const int l15 = lane & 15, quad = lane >> 4;
  const int r0 = tid >> 2, cg = tid & 3;
  // A-frag base in alat2: ((h*16+ks)*512 + tm+wm+i*16+l15)*32 + quad*8
  //                     = aab + ks*16384 + i*512
  const unsigned short* aab =
      alat2 + ((size_t)h * 8192 + tm + wm + l15) * 32 + quad * 8;
  const float* b0 = vb + ((size_t)h * 128 + r0) * 512 + cg * 8;
  const float* b1 = b0 + (size_t)64 * 512;
  floatx4 acc[4][4] = {};
  for (int ks = 0; ks < 16; ++ks) {  // contraction 512 = 16*32
    stage8_f32(b0 + ks * 32, &Bs[tid * 8]);
    stage8_f32(b1 + ks * 32, &Bs[2048 + tid * 8]);
    __syncthreads();
    bf16x8 af[4], bfr[4];
#pragma unroll
    for (int i = 0; i < 4; ++i)
      af[i] = *reinterpret_cast<const bf16x8*>(
          aab + (size_t)ks * 16384 + i * 512);
#pragma unroll
    for (int j = 0; j < 4; ++j)
      bfr[j] = *reinterpret_cast<const bf16x8*>(
          &Bs[(wn + j * 16 + l15) * 32 + quad * 8]);
#pragma unroll
    for (int i = 0; i < 4; ++i)
#pragma unroll
      for (int j = 0; j < 4; ++j)
        acc[i][j] =
            __builtin_amdgcn_mfma_f32_16x16x32_bf16(af[i], bfr[j], acc[i][j], 0, 0, 0);
    __syncthreads();
  }
#pragma unroll
  for (int i = 0; i < 4; ++i) {
    const int row = wm + i * 16 + quad * 4;  // token-local
#pragma unroll
    for (int j = 0; j < 4; ++j) {
      const int col = wn + j * 16 + l15;  // v
#pragma unroll
      for (int r = 0; r < 4; ++r) {
        const int t = tm + row + r;
        out[((size_t)t * 128 + h) * 128 + col] = acc[i][j][r];
      }
    }
  }
}

extern "C" void kernel_launch(void* const* d_in, const int* in_sizes, int n_in,
                              void* d_out, int out_size, void* d_ws, size_t ws_size,
                              hipStream_t stream) {
  const float* q = (const float*)d_in[0];         // (512,128,192)
  const float* kv = (const float*)d_in[1];        // (8192,576)
  const int* topk = (const int*)d_in[2];          // (512,512)
  const float* kb = (const float*)d_in[3];        // (128,512,128)
  const float* vb = (const float*)d_in[4];        // (128,128,512)
  float* out = (float*)d_out;                     // (512,128,128)

  char* ws = (char*)d_ws;
  unsigned short* kvb = (unsigned short*)ws;                       // 9,437,184 B
  unsigned short* qc2 = (unsigned short*)(ws + 9437184);           // 75,497,472 B
  unsigned short* P = (unsigned short*)(ws + 9437184 + 75497472);  // 67,108,864 B
  // lifetime reuse (no growth, 152 MB total):
  unsigned short* P2 = qc2;    // qc2 dead after scores_gemm; softmax writes here
  unsigned short* alat2 = P;   // P dead after softmax; attn writes here

  prep<<<dim3(20992), dim3(256), 0, stream>>>(kv, kvb, q, qc2);
  qlat_gemm<<<dim3(128, 16), dim3(256), 0, stream>>>(q, kb, qc2);
  scores_gemm<<<dim3(512, 4), dim3(256), 0, stream>>>(qc2, kvb, topk, P);
  softmax_rows<<<dim3(16384), dim3(256), 0, stream>>>(P, P2);
  attn_gemm<<<dim3(512), dim3(512), 0, stream>>>(P2, kvb, topk, alat2);
  out_gemm<<<dim3(128, 4), dim3(256), 0, stream>>>(alat2, vb, out);
}

// Round 12
// 361.909 us; speedup vs baseline: 1.1114x; 1.0626x over previous
//
#include <hip/hip_runtime.h>
#include <stdint.h>

// DSA sparse attention, MI355X. T=512 tok, H=128 heads, K=512 selected keys,
// C=576 (512 lora + 64 rope), S=8192 cache rows.
// Pipeline: prep (kv->bf16 + rope copy, SCALE folded), q_lat GEMM,
// scores_fused (QK^T + row softmax -> P2 in attn A-frag order), attn GEMM,
// out GEMM. MFMA tiling per m90/m92.
//
// R11..R16: scores pinned 82-92us across 6 schedule/layout variants
//         (MfmaUtil <=18%) -> gather+LDS throughput bound; R16's fragment
//         swizzle (qc2/alat2) fixed the A-coalescing, scores 82us (best).
// R16->R17: TRAFFIC DELETION - fuse softmax into scores. One 512-thr/8-wave
//         block per token computes the full 128h x 512k row-set (wave = 64h
//         half x 128k quarter, acc 4x8); epilogue: in-lane j-max -> 16-lane
//         shfl_xor -> cross-wave LDS reduce (redmx/redsm, 2 syncthreads) ->
//         exp/normalize in-reg -> write P2 directly (scalar stores; keys are
//         lane-strided so uint4 impossible). Deletes softmax_rows kernel
//         (~25us, 134MB HBM) + 1 launch. K-loop = verified pieces: depth-3
//         4-DMA staging, attn-style single barrier + vmcnt(8) (prologue order
//         DMA0|DMA1|af pinned by fences -> vmcnt(8) retires exactly DMA0),
//         gather indices loaded ONCE (keys fixed per token, only c advances).
//         WS aliasing: P2 -> old P slot (fused kernel reads qc2 while writing
//         P2, so P2 can no longer alias qc2); alat2 -> qc2 slot (dead).

#define SCALE 0.041666666666666664f  // (512+64)^-0.5

typedef __bf16 bf16x8 __attribute__((ext_vector_type(8)));
typedef float floatx4 __attribute__((ext_vector_type(4)));
typedef unsigned int uint32x2 __attribute__((ext_vector_type(2)));
typedef unsigned int uint32x4 __attribute__((ext_vector_type(4)));

static __device__ __forceinline__ unsigned short f2bf(float f) {
  unsigned int u = __builtin_bit_cast(unsigned int, f);
  u += 0x7FFF + ((u >> 16) & 1);  // RNE
  return (unsigned short)(u >> 16);
}
static __device__ __forceinline__ float bf2f(unsigned short h) {
  unsigned int u = ((unsigned int)h) << 16;
  return __builtin_bit_cast(float, u);
}
static __device__ __forceinline__ unsigned int pack2(float lo, float hi) {
  return (unsigned int)f2bf(lo) | ((unsigned int)f2bf(hi) << 16);
}
// async global->LDS, 16B per lane; LDS dest = wave base + lane*16 (m97 pattern)
static __device__ __forceinline__ void ldsdma16(const void* g, void* l) {
  __builtin_amdgcn_global_load_lds(
      (const __attribute__((address_space(1))) void*)g,
      (__attribute__((address_space(3))) void*)l, 16, 0, 0);
}
// IR-level memory fence + machine-sched fence: pins vm-op issue order
static __device__ __forceinline__ void issue_fence() {
  asm volatile("" ::: "memory");
  __builtin_amdgcn_sched_barrier(0);
}
// 32-bit LDS byte address for inline-asm DS ops
static __device__ __forceinline__ unsigned int lds_addr(const void* p) {
  return (unsigned int)(unsigned long long)(
      (__attribute__((address_space(3))) const void*)p);
}
// hardware transpose read: lane l gets column (l&15) of the 4x16 bf16 subtile
#define TR64(dst, addr, OFF) \
  asm volatile("ds_read_b64_tr_b16 %0, %1 offset:" OFF : "=v"(dst) : "v"(addr))

// stage 8 fp32 -> 8 bf16 into LDS (16B aligned)
static __device__ __forceinline__ void stage8_f32(const float* __restrict__ src,
                                                  unsigned short* dst) {
  const float4* s4 = reinterpret_cast<const float4*>(src);
  float4 v0 = s4[0], v1 = s4[1];
  uint4 o;
  o.x = pack2(v0.x, v0.y); o.y = pack2(v0.z, v0.w);
  o.z = pack2(v1.x, v1.y); o.w = pack2(v1.z, v1.w);
  *reinterpret_cast<uint4*>(dst) = o;
}

static __device__ __forceinline__ void mfma_4x4(const unsigned short* As,
                                                const unsigned short* Bs,
                                                int wm, int wn, int l15, int quad,
                                                floatx4 acc[4][4]) {
  bf16x8 af[4], bfr[4];
#pragma unroll
  for (int i = 0; i < 4; ++i)
    af[i] = *reinterpret_cast<const bf16x8*>(&As[(wm + i * 16 + l15) * 32 + quad * 8]);
#pragma unroll
  for (int j = 0; j < 4; ++j)
    bfr[j] = *reinterpret_cast<const bf16x8*>(&Bs[(wn + j * 16 + l15) * 32 + quad * 8]);
#pragma unroll
  for (int i = 0; i < 4; ++i)
#pragma unroll
    for (int j = 0; j < 4; ++j)
      acc[i][j] = __builtin_amdgcn_mfma_f32_16x16x32_bf16(af[i], bfr[j], acc[i][j], 0, 0, 0);
}

// ---------------- K0: kv_cache fp32 -> bf16  +  q_rope * SCALE -> qc2 ----------------
// qc2 layout (A-fragment order): elem (t, h, c) at
// ((t*18 + (c>>5))*128 + h)*32 + (c&31). rope covers c in [512,576) -> ks 16,17.
__global__ void prep(const float* __restrict__ kv, unsigned short* __restrict__ kvb,
                     const float* __restrict__ q, unsigned short* __restrict__ qc2) {
  int b = blockIdx.x;
  if (b < 4608) {
    int i = b * 256 + threadIdx.x;  // per 4 elems, range sized exactly
    float4 v = reinterpret_cast<const float4*>(kv)[i];
    ushort4 o;
    o.x = f2bf(v.x); o.y = f2bf(v.y); o.z = f2bf(v.z); o.w = f2bf(v.w);
    reinterpret_cast<ushort4*>(kvb)[i] = o;
  } else {
    int i = (b - 4608) * 256 + threadIdx.x;  // 512*128*64 total
    int r = i & 63;
    int th = i >> 6;  // t*128 + h
    int t = th >> 7, h = th & 127;
    qc2[(((size_t)t * 18 + 16 + (r >> 5)) * 128 + h) * 32 + (r & 31)] =
        f2bf(q[(size_t)th * 192 + 128 + r] * SCALE);
  }
}

// ---------------- K1: q_lat = per-head (T x 128) @ (512 x 128)^T, * SCALE ----------------
// grid (128, 16): x = h (stride-128 siblings -> same XCD). Writes qc2 frag order.
__global__ __launch_bounds__(256) void qlat_gemm(const float* __restrict__ q,
                                                 const float* __restrict__ kb,
                                                 unsigned short* __restrict__ qc2) {
  const int h = blockIdx.x;
  const int tm = (blockIdx.y & 3) * 128;   // token tile
  const int tn = (blockIdx.y >> 2) * 128;  // lora-dim tile
  __shared__ __align__(16) unsigned short As[128 * 32];
  __shared__ __align__(16) unsigned short Bs[128 * 32];
  const int tid = threadIdx.x;
  const int lane = tid & 63, wave = tid >> 6;
  const int wm = (wave & 1) * 64, wn = (wave >> 1) * 64;
  const int l15 = lane & 15, quad = lane >> 4;
  const int r0 = tid >> 2, cg = tid & 3;  // chunk row, col-group(8)
  const float* a0 = q + ((size_t)(tm + r0) * 128 + h) * 192 + cg * 8;
  const float* a1 = q + ((size_t)(tm + r0 + 64) * 128 + h) * 192 + cg * 8;
  const float* b0 = kb + ((size_t)h * 512 + tn + r0) * 128 + cg * 8;
  const float* b1 = b0 + (size_t)64 * 128;
  floatx4 acc[4][4] = {};
  for (int ks = 0; ks < 4; ++ks) {  // contraction 128 = 4*32
    stage8_f32(a0 + ks * 32, &As[tid * 8]);
    stage8_f32(a1 + ks * 32, &As[2048 + tid * 8]);
    stage8_f32(b0 + ks * 32, &Bs[tid * 8]);
    stage8_f32(b1 + ks * 32, &Bs[2048 + tid * 8]);
    __syncthreads();
    mfma_4x4(As, Bs, wm, wn, l15, quad, acc);
    __syncthreads();
  }
#pragma unroll
  for (int i = 0; i < 4; ++i) {
    const int row = wm + i * 16 + quad * 4;  // token-local
#pragma unroll
    for (int j = 0; j < 4; ++j) {
      const int c = tn + wn + j * 16 + l15;  // lora-dim (global)
      const int ks2 = c >> 5, kk = c & 31;
#pragma unroll
      for (int r = 0; r < 4; ++r) {
        const int t = tm + row + r;
        qc2[(((size_t)t * 18 + ks2) * 128 + h) * 32 + kk] = f2bf(acc[i][j][r] * SCALE);
      }
    }
  }
}

// ---------------- K2: scores_fused = softmax_rows(Qc2 @ KVsel^T) -> P2 ----------------
// grid (512): one block per token, 512 threads / 8 waves.
// Wave = (wave>>2) head-half (64h) x (wave&3) key-quarter (128k); acc 4x8.
// Staging: Bs[3][512k x 32c] (32KB/buf); DMA d=0..3: key=d*128+(tid>>2),
// c-sub=(tid&3)*8 -> lane-linear LDS == row-major [512][32]. Gather indices
// loaded ONCE (keys fixed per token; only the c-slice advances).
// Loop: attn-style single barrier + vmcnt(8): prologue queue [DMA0|DMA1|af]
// pinned by fences -> vmcnt(8) retires exactly DMA0 at iter 0; steady state
// the compiler's af operand-wait retires DMA(ks) one iter early (double-cover).
// Epilogue: row softmax across 512 keys (in-lane j, shfl_xor 16-lane group,
// cross-wave via redmx/redsm LDS), write P2 in attn's A-frag order.
__global__ __launch_bounds__(512) void scores_fused(const unsigned short* __restrict__ qc2,
                                                    const unsigned short* __restrict__ kvb,
                                                    const int* __restrict__ topk,
                                                    unsigned short* __restrict__ P2) {
  const int t = blockIdx.x;
  __shared__ __align__(16) unsigned short Bs[3][512 * 32];  // 96KB
  __shared__ __align__(16) float redmx[128][4];             // 2KB
  __shared__ __align__(16) float redsm[128][4];             // 2KB
  const int tid = threadIdx.x;
  const int lane = tid & 63, wave = tid >> 6;
  const int wm2 = (wave >> 2) * 64;  // head half
  const int wkn = (wave & 3) * 128;  // key quarter
  const int l15 = lane & 15, quad = lane >> 4;
  const int keyD = tid >> 2;         // 0..127
  const int cD = (tid & 3) * 8;
  const int* tkrow = topk + t * 512;
  const int gi0 = tkrow[0 * 128 + keyD];
  const int gi1 = tkrow[1 * 128 + keyD];
  const int gi2 = tkrow[2 * 128 + keyD];
  const int gi3 = tkrow[3 * 128 + keyD];
  const unsigned short* g0 = kvb + (size_t)gi0 * 576 + cD;
  const unsigned short* g1 = kvb + (size_t)gi1 * 576 + cD;
  const unsigned short* g2 = kvb + (size_t)gi2 * 576 + cD;
  const unsigned short* g3 = kvb + (size_t)gi3 * 576 + cD;
  // A-frag base in qc2: ((t*18+ks)*128 + wm2+i*16+l15)*32 + quad*8
  const unsigned short* aab =
      qc2 + ((size_t)t * 2304 + wm2 + l15) * 32 + quad * 8;
  floatx4 acc[4][8] = {};
  // prologue: DMA(0) -> Bs[0] (oldest), DMA(1) -> Bs[1], then af(0) regs
  ldsdma16(g0, &Bs[0][0 * 4096 + tid * 8]);
  ldsdma16(g1, &Bs[0][1 * 4096 + tid * 8]);
  ldsdma16(g2, &Bs[0][2 * 4096 + tid * 8]);
  ldsdma16(g3, &Bs[0][3 * 4096 + tid * 8]);
  issue_fence();
  ldsdma16(g0 + 32, &Bs[1][0 * 4096 + tid * 8]);
  ldsdma16(g1 + 32, &Bs[1][1 * 4096 + tid * 8]);
  ldsdma16(g2 + 32, &Bs[1][2 * 4096 + tid * 8]);
  ldsdma16(g3 + 32, &Bs[1][3 * 4096 + tid * 8]);
  issue_fence();
  bf16x8 af[4], an[4];
#pragma unroll
  for (int i = 0; i < 4; ++i)
    af[i] = *reinterpret_cast<const bf16x8*>(aab + i * 512);
  int bi = 0, bn = 2;  // read buffer, prefetch buffer (=(ks+2)%3)
  for (int ks = 0; ks < 18; ++ks) {  // contraction 576 = 18*32
    asm volatile("s_waitcnt vmcnt(8)" ::: "memory");  // DMA(ks) landed (this wave)
    __builtin_amdgcn_s_barrier();                     // ... for ALL waves
    if (ks < 16) {
      ldsdma16(g0 + (ks + 2) * 32, &Bs[bn][0 * 4096 + tid * 8]);
      ldsdma16(g1 + (ks + 2) * 32, &Bs[bn][1 * 4096 + tid * 8]);
      ldsdma16(g2 + (ks + 2) * 32, &Bs[bn][2 * 4096 + tid * 8]);
      ldsdma16(g3 + (ks + 2) * 32, &Bs[bn][3 * 4096 + tid * 8]);
      issue_fence();  // DMA older than an loads: vm queue order == comments
    }
    if (ks < 17) {
#pragma unroll
      for (int i = 0; i < 4; ++i)
        an[i] = *reinterpret_cast<const bf16x8*>(
            aab + (size_t)(ks + 1) * 4096 + i * 512);
    }
    bf16x8 bfr[8];
#pragma unroll
    for (int j = 0; j < 8; ++j)
      bfr[j] = *reinterpret_cast<const bf16x8*>(
          &Bs[bi][(wkn + j * 16 + l15) * 32 + quad * 8]);
#pragma unroll
    for (int i = 0; i < 4; ++i)
#pragma unroll
      for (int j = 0; j < 8; ++j)
        acc[i][j] =
            __builtin_amdgcn_mfma_f32_16x16x32_bf16(af[i], bfr[j], acc[i][j], 0, 0, 0);
#pragma unroll
    for (int i = 0; i < 4; ++i) af[i] = an[i];
    bi = bi == 2 ? 0 : bi + 1;
    bn = bn == 2 ? 0 : bn + 1;
  }
  // ---- fused softmax epilogue ----
  // D layout: head = wm2 + i*16 + quad*4 + r ; key = wkn + j*16 + l15
  float fm[4][4], inv[4][4];
#pragma unroll
  for (int i = 0; i < 4; ++i)
#pragma unroll
    for (int r = 0; r < 4; ++r) {
      float m = acc[i][0][r];
#pragma unroll
      for (int j = 1; j < 8; ++j) m = fmaxf(m, acc[i][j][r]);
#pragma unroll
      for (int off = 1; off <= 8; off <<= 1) m = fmaxf(m, __shfl_xor(m, off, 64));
      if (l15 == 0) redmx[wm2 + i * 16 + quad * 4 + r][wave & 3] = m;
    }
  __syncthreads();
#pragma unroll
  for (int i = 0; i < 4; ++i)
#pragma unroll
    for (int r = 0; r < 4; ++r) {
      const float4 q4 =
          *reinterpret_cast<const float4*>(redmx[wm2 + i * 16 + quad * 4 + r]);
      fm[i][r] = fmaxf(fmaxf(q4.x, q4.y), fmaxf(q4.z, q4.w));
    }
#pragma unroll
  for (int i = 0; i < 4; ++i)
#pragma unroll
    for (int r = 0; r < 4; ++r) {
      float s = 0.f;
#pragma unroll
      for (int j = 0; j < 8; ++j) {
        const float e = __expf(acc[i][j][r] - fm[i][r]);
        acc[i][j][r] = e;
        s += e;
      }
#pragma unroll
      for (int off = 1; off <= 8; off <<= 1) s += __shfl_xor(s, off, 64);
      if (l15 == 0) redsm[wm2 + i * 16 + quad * 4 + r][wave & 3] = s;
    }
  __syncthreads();
#pragma unroll
  for (int i = 0; i < 4; ++i)
#pragma unroll
    for (int r = 0; r < 4; ++r) {
      const float4 q4 =
          *reinterpret_cast<const float4*>(redsm[wm2 + i * 16 + quad * 4 + r]);
      inv[i][r] = 1.0f / (q4.x + q4.y + q4.z + q4.w);
    }
  // write P2 in attn's A-frag order: ((t*16 + key>>5)*128 + head)*32 + (key&31)
  // key = wkn + j*16 + l15 -> key>>5 = (wave&3)*4 + (j>>1), key&31 = (j&1)*16+l15
#pragma unroll
  for (int i = 0; i < 4; ++i)
#pragma unroll
    for (int j = 0; j < 8; ++j) {
      const int ks2 = (wave & 3) * 4 + (j >> 1);
      const int co = (j & 1) * 16 + l15;
#pragma unroll
      for (int r = 0; r < 4; ++r) {
        const int head = wm2 + i * 16 + quad * 4 + r;
        P2[(((size_t)t * 16 + ks2) * 128 + head) * 32 + co] =
            f2bf(acc[i][j][r] * inv[i][r]);
      }
    }
}

// ---------------- K4: attn_lat = P2 @ KVsel[:, :512], FULL 128h x 512c per block ----------------
// grid (512): one block per token, 512 threads / 8 waves. P2 A-frags read once.
// St[ks tile] = 32 keys x 512 c staged subtiled for tr_read; DMA source
// pre-permuted so lane-linear LDS realizes it. Depth-3 (96KB), vmcnt(4)/iter.
// Epilogue writes alat2 in out_gemm's A-fragment order.
__global__ __launch_bounds__(512) void attn_gemm(const unsigned short* __restrict__ P2,
                                                 const unsigned short* __restrict__ kvb,
                                                 const int* __restrict__ topk,
                                                 unsigned short* __restrict__ alat2) {
  const int t = blockIdx.x;
  __shared__ __align__(16) unsigned short St[3][32 * 512];
  const int tid = threadIdx.x;
  const int lane = tid & 63, wave = tid >> 6;
  const int wm = (wave >> 2) * 64;   // head base (0/64)
  const int wc = wave & 3;           // c-quarter
  const int l15 = lane & 15, quad = lane >> 4;
  const int keyBase = (tid >> 8) * 4 + ((tid >> 1) & 3);
  const int cA = ((tid >> 3) & 31) * 16 + (tid & 1) * 8;
  const int* tkrow = topk + t * 512;
  const unsigned short* a_base =
      P2 + ((size_t)t * 16 * 128 + wm + l15) * 32 + quad * 8;
  const unsigned int tra0 = lds_addr(&St[0][0]) + quad * 8192 + wc * 1024 + l15 * 8;
  floatx4 acc[4][8] = {};
  bf16x8 a_cur[4], a_nxt[4];
  int ip0, ip1, ip2, ip3;  // gather indices for tile ks+2
  {
#pragma unroll
    for (int d = 0; d < 4; ++d) {
      const int k0 = tkrow[d * 8 + keyBase];
      ldsdma16(kvb + (size_t)k0 * 576 + cA, &St[0][d * 4096 + tid * 8]);
    }
#pragma unroll
    for (int i = 0; i < 4; ++i)
      a_cur[i] = *reinterpret_cast<const bf16x8*>(a_base + (size_t)i * 16 * 32);
    ip0 = tkrow[64 + 0 * 8 + keyBase];
    ip1 = tkrow[64 + 1 * 8 + keyBase];
    ip2 = tkrow[64 + 2 * 8 + keyBase];
    ip3 = tkrow[64 + 3 * 8 + keyBase];
    issue_fence();  // St[1] dma stays the YOUNGEST vm group
#pragma unroll
    for (int d = 0; d < 4; ++d) {
      const int k1 = tkrow[32 + d * 8 + keyBase];
      ldsdma16(kvb + (size_t)k1 * 576 + cA, &St[1][d * 4096 + tid * 8]);
    }
  }
  int sti = 0, stp = 2;  // read buffer, prefetch buffer (=(ks+2)%3)
  for (int ks = 0; ks < 16; ++ks) {
    asm volatile("s_waitcnt vmcnt(4)" ::: "memory");
    __builtin_amdgcn_s_barrier();  // St[sti] full for all waves; St[stp] free
    const unsigned int tra = tra0 + sti * 32768;
    uint32x2 rl0, rl1, rl2, rl3, rl4, rl5, rl6, rl7;
    uint32x2 rh0, rh1, rh2, rh3, rh4, rh5, rh6, rh7;
    TR64(rl0, tra, "0");    TR64(rh0, tra, "4096");
    TR64(rl1, tra, "128");  TR64(rh1, tra, "4224");
    TR64(rl2, tra, "256");  TR64(rh2, tra, "4352");
    TR64(rl3, tra, "384");  TR64(rh3, tra, "4480");
    TR64(rl4, tra, "512");  TR64(rh4, tra, "4608");
    TR64(rl5, tra, "640");  TR64(rh5, tra, "4736");
    TR64(rl6, tra, "768");  TR64(rh6, tra, "4864");
    TR64(rl7, tra, "896");  TR64(rh7, tra, "4992");
    if (ks < 15) {
#pragma unroll
      for (int i = 0; i < 4; ++i)
        a_nxt[i] = *reinterpret_cast<const bf16x8*>(
            a_base + ((size_t)(ks + 1) * 128 + i * 16) * 32);
    }
    if (ks < 14) {
      const int d0 = ip0, d1 = ip1, d2 = ip2, d3 = ip3;
      if (ks < 13) {
        ip0 = tkrow[(ks + 3) * 32 + 0 * 8 + keyBase];
        ip1 = tkrow[(ks + 3) * 32 + 1 * 8 + keyBase];
        ip2 = tkrow[(ks + 3) * 32 + 2 * 8 + keyBase];
        ip3 = tkrow[(ks + 3) * 32 + 3 * 8 + keyBase];
      }
      issue_fence();  // DMA issued last so it stays the youngest vm group
      ldsdma16(kvb + (size_t)d0 * 576 + cA, &St[stp][0 * 4096 + tid * 8]);
      ldsdma16(kvb + (size_t)d1 * 576 + cA, &St[stp][1 * 4096 + tid * 8]);
      ldsdma16(kvb + (size_t)d2 * 576 + cA, &St[stp][2 * 4096 + tid * 8]);
      ldsdma16(kvb + (size_t)d3 * 576 + cA, &St[stp][3 * 4096 + tid * 8]);
    }
    asm volatile("s_waitcnt lgkmcnt(0)");   // tr_reads complete
    __builtin_amdgcn_sched_barrier(0);      // rule #18: pin MFMAs after the wait
    bf16x8 bfr[8];
    {
      uint32x4 w;
      w.x = rl0.x; w.y = rl0.y; w.z = rh0.x; w.w = rh0.y; bfr[0] = __builtin_bit_cast(bf16x8, w);
      w.x = rl1.x; w.y = rl1.y; w.z = rh1.x; w.w = rh1.y; bfr[1] = __builtin_bit_cast(bf16x8, w);
      w.x = rl2.x; w.y = rl2.y; w.z = rh2.x; w.w = rh2.y; bfr[2] = __builtin_bit_cast(bf16x8, w);
      w.x = rl3.x; w.y = rl3.y; w.z = rh3.x; w.w = rh3.y; bfr[3] = __builtin_bit_cast(bf16x8, w);
      w.x = rl4.x; w.y = rl4.y; w.z = rh4.x; w.w = rh4.y; bfr[4] = __builtin_bit_cast(bf16x8, w);
      w.x = rl5.x; w.y = rl5.y; w.z = rh5.x; w.w = rh5.y; bfr[5] = __builtin_bit_cast(bf16x8, w);
      w.x = rl6.x; w.y = rl6.y; w.z = rh6.x; w.w = rh6.y; bfr[6] = __builtin_bit_cast(bf16x8, w);
      w.x = rl7.x; w.y = rl7.y; w.z = rh7.x; w.w = rh7.y; bfr[7] = __builtin_bit_cast(bf16x8, w);
    }
#pragma unroll
    for (int i = 0; i < 4; ++i)
#pragma unroll
      for (int j = 0; j < 8; ++j)
        acc[i][j] =
            __builtin_amdgcn_mfma_f32_16x16x32_bf16(a_cur[i], bfr[j], acc[i][j], 0, 0, 0);
#pragma unroll
    for (int i = 0; i < 4; ++i) a_cur[i] = a_nxt[i];
    sti = sti == 2 ? 0 : sti + 1;
    stp = stp == 2 ? 0 : stp + 1;
  }
  // write alat2 in out_gemm's A-fragment order:
  // elem (h=row+r, t, c) at ((h*16 + (c>>5))*512 + t)*32 + (c&31)
#pragma unroll
  for (int i = 0; i < 4; ++i) {
    const int row = wm + i * 16 + quad * 4;  // head
#pragma unroll
    for (int j = 0; j < 8; ++j) {
      const int c = wc * 128 + j * 16 + l15;  // c
      const int ks2 = c >> 5, kk = c & 31;
#pragma unroll
      for (int r = 0; r < 4; ++r)
        alat2[(((size_t)(row + r) * 16 + ks2) * 512 + t) * 32 + kk] =
            f2bf(acc[i][j][r]);
    }
  }
}

// ---------------- K5: out (128t x 128v tile) = attn_lat[h] @ v_b[h]^T ----------------
// grid (128, 4): x = h (stride-128 siblings -> same XCD). A-frags DIRECT from
// alat2 (fragment order -> coalesced); only B (fp32 vb) staged. __syncthreads.
__global__ __launch_bounds__(256) void out_gemm(const unsigned short* __restrict__ alat2,
                                                const float* __restrict__ vb,
                                                float* __restrict__ out) {
  const int h = blockIdx.x;
  const int tm = blockIdx.y * 128;  // token tile
  __shared__ __align__(16) unsigned short Bs[128 * 32];
  const int tid = threadIdx.x;
  const int lane = tid & 63, wave = tid >> 6;
  const int wm = (wave & 1) * 64, wn = (wave >> 1) * 64;
  const int l15 = lane & 15, quad = lane >> 4;
  const int r0 = tid >> 2, cg = tid & 3;
  const unsigned short* aab =
      alat2 + ((size_t)h * 8192 + tm + wm + l15) * 32 + quad * 8;
  const float* b0 = vb + ((size_t)h * 128 + r0) * 512 + cg * 8;
  const float* b1 = b0 + (size_t)64 * 512;
  floatx4 acc[4][4] = {};
  for (int ks = 0; ks < 16; ++ks) {  // contraction 512 = 16*32
    stage8_f32(b0 + ks * 32, &Bs[tid * 8]);
    stage8_f32(b1 + ks * 32, &Bs[2048 + tid * 8]);
    __syncthreads();
    bf16x8 af[4], bfr[4];
#pragma unroll
    for (int i = 0; i < 4; ++i)
      af[i] = *reinterpret_cast<const bf16x8*>(
          aab + (size_t)ks * 16384 + i * 512);
#pragma unroll
    for (int j = 0; j < 4; ++j)
      bfr[j] = *reinterpret_cast<const bf16x8*>(
          &Bs[(wn + j * 16 + l15) * 32 + quad * 8]);
#pragma unroll
    for (int i = 0; i < 4; ++i)
#pragma unroll
      for (int j = 0; j < 4; ++j)
        acc[i][j] =
            __builtin_amdgcn_mfma_f32_16x16x32_bf16(af[i], bfr[j], acc[i][j], 0, 0, 0);
    __syncthreads();
  }
#pragma unroll
  for (int i = 0; i < 4; ++i) {
    const int row = wm + i * 16 + quad * 4;  // token-local
#pragma unroll
    for (int j = 0; j < 4; ++j) {
      const int col = wn + j * 16 + l15;  // v
#pragma unroll
      for (int r = 0; r < 4; ++r) {
        const int t = tm + row + r;
        out[((size_t)t * 128 + h) * 128 + col] = acc[i][j][r];
      }
    }
  }
}

extern "C" void kernel_launch(void* const* d_in, const int* in_sizes, int n_in,
                              void* d_out, int out_size, void* d_ws, size_t ws_size,
                              hipStream_t stream) {
  const float* q = (const float*)d_in[0];         // (512,128,192)
  const float* kv = (const float*)d_in[1];        // (8192,576)
  const int* topk = (const int*)d_in[2];          // (512,512)
  const float* kb = (const float*)d_in[3];        // (128,512,128)
  const float* vb = (const float*)d_in[4];        // (128,128,512)
  float* out = (float*)d_out;                     // (512,128,128)

  char* ws = (char*)d_ws;
  unsigned short* kvb = (unsigned short*)ws;                        // 9,437,184 B
  unsigned short* qc2 = (unsigned short*)(ws + 9437184);            // 75,497,472 B
  unsigned short* P2 = (unsigned short*)(ws + 9437184 + 75497472);  // 67,108,864 B
  // P2 must NOT alias qc2 (scores_fused reads qc2 while writing P2).
  // alat2 reuses qc2 (dead after scores_fused). Total ws unchanged: 152 MB.
  unsigned short* alat2 = qc2;

  prep<<<dim3(20992), dim3(256), 0, stream>>>(kv, kvb, q, qc2);
  qlat_gemm<<<dim3(128, 16), dim3(256), 0, stream>>>(q, kb, qc2);
  scores_fused<<<dim3(512), dim3(512), 0, stream>>>(qc2, kvb, topk, P2);
  attn_gemm<<<dim3(512), dim3(512), 0, stream>>>(P2, kvb, topk, alat2);
  out_gemm<<<dim3(128, 4), dim3(256), 0, stream>>>(alat2, vb, out);
}

// Round 14
// 352.868 us; speedup vs baseline: 1.1399x; 1.0256x over previous
//
#include <hip/hip_runtime.h>
#include <stdint.h>

// DSA sparse attention, MI355X. T=512 tok, H=128 heads, K=512 selected keys,
// C=576 (512 lora + 64 rope), S=8192 cache rows.
// Pipeline: prep (kv->bf16 + rope copy, SCALE folded), q_lat GEMM,
// scores_fused (QK^T + row softmax -> P2 in attn A-frag order), attn GEMM,
// out GEMM. MFMA tiling per m90/m92.
//
// R16->R17: softmax fused into scores (P roundtrip deleted): 384.6->361.9us.
// R17->R18: OCCUPANCY round. scores_fused diagnosis: 1 block/CU (102KB LDS),
//         8 waves = 2/SIMD; per-iter 5.6k cyc vs ~3.3k of actual work -> lock-
//         step starvation, nothing saturated (Mfma 18%, VALU 23%, HBM 26%).
//         Fix: 1024-thread blocks, 16 waves (4/SIMD), wave grid 4hq x 4kq,
//         acc[2][8]=64 VGPR (fits 128-reg cap); staging depth-2 (scores Bs[2]
//         64KB+4KB red, attn St[2] 64KB); scores vmcnt(2) uniform, attn
//         vmcnt(4)/vmcnt(2@ks=15); attn TR64s in two j-batches.
// R18->R19: infra-failed round (container failed twice); resubmit unchanged
//         after re-audit: both vm-queues traced per-iter (uniform vmcnt(2)
//         correct incl. tail; an(ks) older than DMA(ks+1) so compiler operand
//         waits never over-retire); depth-2 reuse guarded by barrier+lgkm
//         drain. Decision rule stands: VGPR=128+scratch & flat -> revert 512.

#define SCALE 0.041666666666666664f  // (512+64)^-0.5

typedef __bf16 bf16x8 __attribute__((ext_vector_type(8)));
typedef float floatx4 __attribute__((ext_vector_type(4)));
typedef unsigned int uint32x2 __attribute__((ext_vector_type(2)));
typedef unsigned int uint32x4 __attribute__((ext_vector_type(4)));

static __device__ __forceinline__ unsigned short f2bf(float f) {
  unsigned int u = __builtin_bit_cast(unsigned int, f);
  u += 0x7FFF + ((u >> 16) & 1);  // RNE
  return (unsigned short)(u >> 16);
}
static __device__ __forceinline__ float bf2f(unsigned short h) {
  unsigned int u = ((unsigned int)h) << 16;
  return __builtin_bit_cast(float, u);
}
static __device__ __forceinline__ unsigned int pack2(float lo, float hi) {
  return (unsigned int)f2bf(lo) | ((unsigned int)f2bf(hi) << 16);
}
// async global->LDS, 16B per lane; LDS dest = wave base + lane*16 (m97 pattern)
static __device__ __forceinline__ void ldsdma16(const void* g, void* l) {
  __builtin_amdgcn_global_load_lds(
      (const __attribute__((address_space(1))) void*)g,
      (__attribute__((address_space(3))) void*)l, 16, 0, 0);
}
// IR-level memory fence + machine-sched fence: pins vm-op issue order
static __device__ __forceinline__ void issue_fence() {
  asm volatile("" ::: "memory");
  __builtin_amdgcn_sched_barrier(0);
}
// 32-bit LDS byte address for inline-asm DS ops
static __device__ __forceinline__ unsigned int lds_addr(const void* p) {
  return (unsigned int)(unsigned long long)(
      (__attribute__((address_space(3))) const void*)p);
}
// hardware transpose read: lane l gets column (l&15) of the 4x16 bf16 subtile
#define TR64(dst, addr, OFF) \
  asm volatile("ds_read_b64_tr_b16 %0, %1 offset:" OFF : "=v"(dst) : "v"(addr))

// stage 8 fp32 -> 8 bf16 into LDS (16B aligned)
static __device__ __forceinline__ void stage8_f32(const float* __restrict__ src,
                                                  unsigned short* dst) {
  const float4* s4 = reinterpret_cast<const float4*>(src);
  float4 v0 = s4[0], v1 = s4[1];
  uint4 o;
  o.x = pack2(v0.x, v0.y); o.y = pack2(v0.z, v0.w);
  o.z = pack2(v1.x, v1.y); o.w = pack2(v1.z, v1.w);
  *reinterpret_cast<uint4*>(dst) = o;
}

static __device__ __forceinline__ void mfma_4x4(const unsigned short* As,
                                                const unsigned short* Bs,
                                                int wm, int wn, int l15, int quad,
                                                floatx4 acc[4][4]) {
  bf16x8 af[4], bfr[4];
#pragma unroll
  for (int i = 0; i < 4; ++i)
    af[i] = *reinterpret_cast<const bf16x8*>(&As[(wm + i * 16 + l15) * 32 + quad * 8]);
#pragma unroll
  for (int j = 0; j < 4; ++j)
    bfr[j] = *reinterpret_cast<const bf16x8*>(&Bs[(wn + j * 16 + l15) * 32 + quad * 8]);
#pragma unroll
  for (int i = 0; i < 4; ++i)
#pragma unroll
    for (int j = 0; j < 4; ++j)
      acc[i][j] = __builtin_amdgcn_mfma_f32_16x16x32_bf16(af[i], bfr[j], acc[i][j], 0, 0, 0);
}

// ---------------- K0: kv_cache fp32 -> bf16  +  q_rope * SCALE -> qc2 ----------------
// qc2 layout (A-fragment order): elem (t, h, c) at
// ((t*18 + (c>>5))*128 + h)*32 + (c&31). rope covers c in [512,576) -> ks 16,17.
__global__ void prep(const float* __restrict__ kv, unsigned short* __restrict__ kvb,
                     const float* __restrict__ q, unsigned short* __restrict__ qc2) {
  int b = blockIdx.x;
  if (b < 4608) {
    int i = b * 256 + threadIdx.x;  // per 4 elems, range sized exactly
    float4 v = reinterpret_cast<const float4*>(kv)[i];
    ushort4 o;
    o.x = f2bf(v.x); o.y = f2bf(v.y); o.z = f2bf(v.z); o.w = f2bf(v.w);
    reinterpret_cast<ushort4*>(kvb)[i] = o;
  } else {
    int i = (b - 4608) * 256 + threadIdx.x;  // 512*128*64 total
    int r = i & 63;
    int th = i >> 6;  // t*128 + h
    int t = th >> 7, h = th & 127;
    qc2[(((size_t)t * 18 + 16 + (r >> 5)) * 128 + h) * 32 + (r & 31)] =
        f2bf(q[(size_t)th * 192 + 128 + r] * SCALE);
  }
}

// ---------------- K1: q_lat = per-head (T x 128) @ (512 x 128)^T, * SCALE ----------------
// grid (128, 16): x = h (stride-128 siblings -> same XCD). Writes qc2 frag order.
__global__ __launch_bounds__(256) void qlat_gemm(const float* __restrict__ q,
                                                 const float* __restrict__ kb,
                                                 unsigned short* __restrict__ qc2) {
  const int h = blockIdx.x;
  const int tm = (blockIdx.y & 3) * 128;   // token tile
  const int tn = (blockIdx.y >> 2) * 128;  // lora-dim tile
  __shared__ __align__(16) unsigned short As[128 * 32];
  __shared__ __align__(16) unsigned short Bs[128 * 32];
  const int tid = threadIdx.x;
  const int lane = tid & 63, wave = tid >> 6;
  const int wm = (wave & 1) * 64, wn = (wave >> 1) * 64;
  const int l15 = lane & 15, quad = lane >> 4;
  const int r0 = tid >> 2, cg = tid & 3;  // chunk row, col-group(8)
  const float* a0 = q + ((size_t)(tm + r0) * 128 + h) * 192 + cg * 8;
  const float* a1 = q + ((size_t)(tm + r0 + 64) * 128 + h) * 192 + cg * 8;
  const float* b0 = kb + ((size_t)h * 512 + tn + r0) * 128 + cg * 8;
  const float* b1 = b0 + (size_t)64 * 128;
  floatx4 acc[4][4] = {};
  for (int ks = 0; ks < 4; ++ks) {  // contraction 128 = 4*32
    stage8_f32(a0 + ks * 32, &As[tid * 8]);
    stage8_f32(a1 + ks * 32, &As[2048 + tid * 8]);
    stage8_f32(b0 + ks * 32, &Bs[tid * 8]);
    stage8_f32(b1 + ks * 32, &Bs[2048 + tid * 8]);
    __syncthreads();
    mfma_4x4(As, Bs, wm, wn, l15, quad, acc);
    __syncthreads();
  }
#pragma unroll
  for (int i = 0; i < 4; ++i) {
    const int row = wm + i * 16 + quad * 4;  // token-local
#pragma unroll
    for (int j = 0; j < 4; ++j) {
      const int c = tn + wn + j * 16 + l15;  // lora-dim (global)
      const int ks2 = c >> 5, kk = c & 31;
#pragma unroll
      for (int r = 0; r < 4; ++r) {
        const int t = tm + row + r;
        qc2[(((size_t)t * 18 + ks2) * 128 + h) * 32 + kk] = f2bf(acc[i][j][r] * SCALE);
      }
    }
  }
}

// ---------------- K2: scores_fused = softmax_rows(Qc2 @ KVsel^T) -> P2 ----------------
// grid (512): one block per token, 1024 threads / 16 waves (4/SIMD).
// Wave = (wave>>2) head-quarter (32h) x (wave&3) key-quarter (128k); acc 2x8
// (64 VGPR). Staging: Bs[2][512x32] (64KB, depth-2); DMA d=0,1:
// key=d*256+(tid>>2), c-sub=(tid&3)*8 -> lane-linear LDS == row-major [512][32].
// Gather indices loaded ONCE. vm-queue at iter top: [DMA(ks)x2, an(ks)x2] ->
// vmcnt(2) retires DMA(ks) (fences pin DMA-before-an). Depth-2 reuse safe:
// DMA into (ks+1)&1 issued after the barrier postdating all reads of it.
__global__ __launch_bounds__(1024) void scores_fused(const unsigned short* __restrict__ qc2,
                                                     const unsigned short* __restrict__ kvb,
                                                     const int* __restrict__ topk,
                                                     unsigned short* __restrict__ P2) {
  const int t = blockIdx.x;
  __shared__ __align__(16) unsigned short Bs[2][512 * 32];  // 64KB
  __shared__ __align__(16) float redmx[128][4];             // 2KB
  __shared__ __align__(16) float redsm[128][4];             // 2KB
  const int tid = threadIdx.x;
  const int lane = tid & 63, wave = tid >> 6;  // 0..15
  const int wm2 = (wave >> 2) * 32;  // head quarter
  const int wkq = wave & 3;          // key quarter
  const int l15 = lane & 15, quad = lane >> 4;
  const int keyD = tid >> 2;         // 0..255
  const int cD = (tid & 3) * 8;
  const int* tkrow = topk + t * 512;
  const int gi0 = tkrow[keyD];
  const int gi1 = tkrow[256 + keyD];
  const unsigned short* g0 = kvb + (size_t)gi0 * 576 + cD;
  const unsigned short* g1 = kvb + (size_t)gi1 * 576 + cD;
  // A-frag base in qc2: ((t*18+ks)*128 + wm2+i*16+l15)*32 + quad*8
  const unsigned short* aab =
      qc2 + ((size_t)t * 2304 + wm2 + l15) * 32 + quad * 8;
  floatx4 acc[2][8] = {};
  // prologue: DMA(0) -> Bs[0] (oldest, pinned), then af(0) regs
  ldsdma16(g0, &Bs[0][tid * 8]);
  ldsdma16(g1, &Bs[0][8192 + tid * 8]);
  issue_fence();
  bf16x8 af[2], an[2];
  af[0] = *reinterpret_cast<const bf16x8*>(aab);
  af[1] = *reinterpret_cast<const bf16x8*>(aab + 512);
  for (int ks = 0; ks < 18; ++ks) {  // contraction 576 = 18*32
    asm volatile("s_waitcnt vmcnt(2)" ::: "memory");  // DMA(ks) landed (this wave)
    __builtin_amdgcn_s_barrier();                     // ... for ALL waves
    if (ks < 17) {
      ldsdma16(g0 + (ks + 1) * 32, &Bs[(ks + 1) & 1][tid * 8]);
      ldsdma16(g1 + (ks + 1) * 32, &Bs[(ks + 1) & 1][8192 + tid * 8]);
      issue_fence();  // DMA older than an loads
      an[0] = *reinterpret_cast<const bf16x8*>(aab + (size_t)(ks + 1) * 4096);
      an[1] = *reinterpret_cast<const bf16x8*>(aab + (size_t)(ks + 1) * 4096 + 512);
    }
    const unsigned short* bb = &Bs[ks & 1][0];
#pragma unroll
    for (int j = 0; j < 8; ++j) {
      const bf16x8 bfr = *reinterpret_cast<const bf16x8*>(
          &bb[(wkq * 128 + j * 16 + l15) * 32 + quad * 8]);
      acc[0][j] = __builtin_amdgcn_mfma_f32_16x16x32_bf16(af[0], bfr, acc[0][j], 0, 0, 0);
      acc[1][j] = __builtin_amdgcn_mfma_f32_16x16x32_bf16(af[1], bfr, acc[1][j], 0, 0, 0);
    }
    af[0] = an[0];
    af[1] = an[1];
  }
  // ---- fused softmax epilogue ----
  // D layout: head = wm2 + i*16 + quad*4 + r ; key = wkq*128 + j*16 + l15
  float fm[2][4], inv[2][4];
#pragma unroll
  for (int i = 0; i < 2; ++i)
#pragma unroll
    for (int r = 0; r < 4; ++r) {
      float m = acc[i][0][r];
#pragma unroll
      for (int j = 1; j < 8; ++j) m = fmaxf(m, acc[i][j][r]);
#pragma unroll
      for (int off = 1; off <= 8; off <<= 1) m = fmaxf(m, __shfl_xor(m, off, 64));
      if (l15 == 0) redmx[wm2 + i * 16 + quad * 4 + r][wkq] = m;
    }
  __syncthreads();
#pragma unroll
  for (int i = 0; i < 2; ++i)
#pragma unroll
    for (int r = 0; r < 4; ++r) {
      const float4 q4 =
          *reinterpret_cast<const float4*>(redmx[wm2 + i * 16 + quad * 4 + r]);
      fm[i][r] = fmaxf(fmaxf(q4.x, q4.y), fmaxf(q4.z, q4.w));
    }
#pragma unroll
  for (int i = 0; i < 2; ++i)
#pragma unroll
    for (int r = 0; r < 4; ++r) {
      float s = 0.f;
#pragma unroll
      for (int j = 0; j < 8; ++j) {
        const float e = __expf(acc[i][j][r] - fm[i][r]);
        acc[i][j][r] = e;
        s += e;
      }
#pragma unroll
      for (int off = 1; off <= 8; off <<= 1) s += __shfl_xor(s, off, 64);
      if (l15 == 0) redsm[wm2 + i * 16 + quad * 4 + r][wkq] = s;
    }
  __syncthreads();
#pragma unroll
  for (int i = 0; i < 2; ++i)
#pragma unroll
    for (int r = 0; r < 4; ++r) {
      const float4 q4 =
          *reinterpret_cast<const float4*>(redsm[wm2 + i * 16 + quad * 4 + r]);
      inv[i][r] = 1.0f / (q4.x + q4.y + q4.z + q4.w);
    }
  // write P2 in attn's A-frag order: ((t*16 + key>>5)*128 + head)*32 + (key&31)
#pragma unroll
  for (int i = 0; i < 2; ++i)
#pragma unroll
    for (int j = 0; j < 8; ++j) {
      const int ks2 = wkq * 4 + (j >> 1);
      const int co = (j & 1) * 16 + l15;
#pragma unroll
      for (int r = 0; r < 4; ++r) {
        const int head = wm2 + i * 16 + quad * 4 + r;
        P2[(((size_t)t * 16 + ks2) * 128 + head) * 32 + co] =
            f2bf(acc[i][j][r] * inv[i][r]);
      }
    }
}

// ---------------- K4: attn_lat = P2 @ KVsel[:, :512], FULL 128h x 512c per block ----------------
// grid (512): one block per token, 1024 threads / 16 waves (4/SIMD).
// Wave = (wave>>2) head-quarter (32h) x (wave&3) c-quarter (128c); acc 2x8.
// St[2][32k x 512c] (64KB, depth-2) subtiled for tr_read; DMA d=0,1:
// key = d*16 + (tid>>8)*4 + ((tid>>1)&3), c = ((tid>>3)&31)*16 + (tid&1)*8,
// dest = d*16KB + tid*16 (inverse of the subtile map). vm-queue at iter top:
// ks<15: [DMA x2, a x2, idx x2] -> vmcnt(4); ks=15: [DMA x2, a x2] -> vmcnt(2).
// TR64s in two j-batches (halved transient reg liveness).
__global__ __launch_bounds__(1024) void attn_gemm(const unsigned short* __restrict__ P2,
                                                  const unsigned short* __restrict__ kvb,
                                                  const int* __restrict__ topk,
                                                  unsigned short* __restrict__ alat2) {
  const int t = blockIdx.x;
  __shared__ __align__(16) unsigned short St[2][32 * 512];  // 64KB
  const int tid = threadIdx.x;
  const int lane = tid & 63, wave = tid >> 6;  // 0..15
  const int wm = (wave >> 2) * 32;  // head quarter
  const int wc = wave & 3;          // c-quarter
  const int l15 = lane & 15, quad = lane >> 4;
  const int kb2 = (tid >> 8) * 4 + ((tid >> 1) & 3);     // 0..15
  const int cA = ((tid >> 3) & 31) * 16 + (tid & 1) * 8; // 0..504
  const int* tkrow = topk + t * 512;
  // A-fragment base: P2[((t*16+ks)*128 + wm+i*16+l15)*32 + quad*8]
  const unsigned short* a_base =
      P2 + ((size_t)t * 2048 + wm + l15) * 32 + quad * 8;
  // tr_read: subtile (kq=2*quad+h01, ct=wc*8+j) at byte (kq*32+ct)*128;
  // lane addr = quad*8192 + wc*1024 + l15*8; offsets j*128 (+4096 for h01=1)
  const unsigned int tra0 = lds_addr(&St[0][0]) + quad * 8192 + wc * 1024 + l15 * 8;
  floatx4 acc[2][8] = {};
  bf16x8 a_cur[2], a_nxt[2];
  int ip0, ip1;  // gather indices for tile ks+1
  {
    const int k00 = tkrow[kb2];
    const int k01 = tkrow[16 + kb2];
    ldsdma16(kvb + (size_t)k00 * 576 + cA, &St[0][tid * 8]);
    ldsdma16(kvb + (size_t)k01 * 576 + cA, &St[0][8192 + tid * 8]);
    issue_fence();
    a_cur[0] = *reinterpret_cast<const bf16x8*>(a_base);
    a_cur[1] = *reinterpret_cast<const bf16x8*>(a_base + 512);
    ip0 = tkrow[32 + kb2];
    ip1 = tkrow[48 + kb2];
    issue_fence();
  }
  for (int ks = 0; ks < 16; ++ks) {
    if (ks < 15) asm volatile("s_waitcnt vmcnt(4)" ::: "memory");  // DMA(ks) landed
    else         asm volatile("s_waitcnt vmcnt(2)" ::: "memory");
    __builtin_amdgcn_s_barrier();  // St[ks&1] full for all waves; other buf free
    const unsigned int tra = tra0 + (ks & 1) * 32768;
    if (ks < 15) {
      ldsdma16(kvb + (size_t)ip0 * 576 + cA, &St[(ks + 1) & 1][tid * 8]);
      ldsdma16(kvb + (size_t)ip1 * 576 + cA, &St[(ks + 1) & 1][8192 + tid * 8]);
      issue_fence();  // DMA oldest of this iter's vm ops
      a_nxt[0] = *reinterpret_cast<const bf16x8*>(a_base + (size_t)(ks + 1) * 4096);
      a_nxt[1] = *reinterpret_cast<const bf16x8*>(a_base + (size_t)(ks + 1) * 4096 + 512);
      if (ks < 14) {
        ip0 = tkrow[(ks + 2) * 32 + kb2];
        ip1 = tkrow[(ks + 2) * 32 + 16 + kb2];
      }
    }
    // j-batch 0: ct = wc*8 + 0..3
    {
      uint32x2 rl0, rl1, rl2, rl3, rh0, rh1, rh2, rh3;
      TR64(rl0, tra, "0");    TR64(rh0, tra, "4096");
      TR64(rl1, tra, "128");  TR64(rh1, tra, "4224");
      TR64(rl2, tra, "256");  TR64(rh2, tra, "4352");
      TR64(rl3, tra, "384");  TR64(rh3, tra, "4480");
      asm volatile("s_waitcnt lgkmcnt(0)");
      __builtin_amdgcn_sched_barrier(0);  // rule #18
      uint32x4 w;
      bf16x8 bfr;
      w.x = rl0.x; w.y = rl0.y; w.z = rh0.x; w.w = rh0.y; bfr = __builtin_bit_cast(bf16x8, w);
      acc[0][0] = __builtin_amdgcn_mfma_f32_16x16x32_bf16(a_cur[0], bfr, acc[0][0], 0, 0, 0);
      acc[1][0] = __builtin_amdgcn_mfma_f32_16x16x32_bf16(a_cur[1], bfr, acc[1][0], 0, 0, 0);
      w.x = rl1.x; w.y = rl1.y; w.z = rh1.x; w.w = rh1.y; bfr = __builtin_bit_cast(bf16x8, w);
      acc[0][1] = __builtin_amdgcn_mfma_f32_16x16x32_bf16(a_cur[0], bfr, acc[0][1], 0, 0, 0);
      acc[1][1] = __builtin_amdgcn_mfma_f32_16x16x32_bf16(a_cur[1], bfr, acc[1][1], 0, 0, 0);
      w.x = rl2.x; w.y = rl2.y; w.z = rh2.x; w.w = rh2.y; bfr = __builtin_bit_cast(bf16x8, w);
      acc[0][2] = __builtin_amdgcn_mfma_f32_16x16x32_bf16(a_cur[0], bfr, acc[0][2], 0, 0, 0);
      acc[1][2] = __builtin_amdgcn_mfma_f32_16x16x32_bf16(a_cur[1], bfr, acc[1][2], 0, 0, 0);
      w.x = rl3.x; w.y = rl3.y; w.z = rh3.x; w.w = rh3.y; bfr = __builtin_bit_cast(bf16x8, w);
      acc[0][3] = __builtin_amdgcn_mfma_f32_16x16x32_bf16(a_cur[0], bfr, acc[0][3], 0, 0, 0);
      acc[1][3] = __builtin_amdgcn_mfma_f32_16x16x32_bf16(a_cur[1], bfr, acc[1][3], 0, 0, 0);
    }
    // j-batch 1: ct = wc*8 + 4..7
    {
      uint32x2 rl4, rl5, rl6, rl7, rh4, rh5, rh6, rh7;
      TR64(rl4, tra, "512");  TR64(rh4, tra, "4608");
      TR64(rl5, tra, "640");  TR64(rh5, tra, "4736");
      TR64(rl6, tra, "768");  TR64(rh6, tra, "4864");
      TR64(rl7, tra, "896");  TR64(rh7, tra, "4992");
      asm volatile("s_waitcnt lgkmcnt(0)");
      __builtin_amdgcn_sched_barrier(0);  // rule #18
      uint32x4 w;
      bf16x8 bfr;
      w.x = rl4.x; w.y = rl4.y; w.z = rh4.x; w.w = rh4.y; bfr = __builtin_bit_cast(bf16x8, w);
      acc[0][4] = __builtin_amdgcn_mfma_f32_16x16x32_bf16(a_cur[0], bfr, acc[0][4], 0, 0, 0);
      acc[1][4] = __builtin_amdgcn_mfma_f32_16x16x32_bf16(a_cur[1], bfr, acc[1][4], 0, 0, 0);
      w.x = rl5.x; w.y = rl5.y; w.z = rh5.x; w.w = rh5.y; bfr = __builtin_bit_cast(bf16x8, w);
      acc[0][5] = __builtin_amdgcn_mfma_f32_16x16x32_bf16(a_cur[0], bfr, acc[0][5], 0, 0, 0);
      acc[1][5] = __builtin_amdgcn_mfma_f32_16x16x32_bf16(a_cur[1], bfr, acc[1][5], 0, 0, 0);
      w.x = rl6.x; w.y = rl6.y; w.z = rh6.x; w.w = rh6.y; bfr = __builtin_bit_cast(bf16x8, w);
      acc[0][6] = __builtin_amdgcn_mfma_f32_16x16x32_bf16(a_cur[0], bfr, acc[0][6], 0, 0, 0);
      acc[1][6] = __builtin_amdgcn_mfma_f32_16x16x32_bf16(a_cur[1], bfr, acc[1][6], 0, 0, 0);
      w.x = rl7.x; w.y = rl7.y; w.z = rh7.x; w.w = rh7.y; bfr = __builtin_bit_cast(bf16x8, w);
      acc[0][7] = __builtin_amdgcn_mfma_f32_16x16x32_bf16(a_cur[0], bfr, acc[0][7], 0, 0, 0);
      acc[1][7] = __builtin_amdgcn_mfma_f32_16x16x32_bf16(a_cur[1], bfr, acc[1][7], 0, 0, 0);
    }
    a_cur[0] = a_nxt[0];
    a_cur[1] = a_nxt[1];
  }
  // write alat2 in out_gemm's A-fragment order:
  // elem (h=row+r, t, c) at ((h*16 + (c>>5))*512 + t)*32 + (c&31)
#pragma unroll
  for (int i = 0; i < 2; ++i) {
    const int row = wm + i * 16 + quad * 4;  // head
#pragma unroll
    for (int j = 0; j < 8; ++j) {
      const int c = wc * 128 + j * 16 + l15;  // c
      const int ks2 = c >> 5, kk = c & 31;
#pragma unroll
      for (int r = 0; r < 4; ++r)
        alat2[(((size_t)(row + r) * 16 + ks2) * 512 + t) * 32 + kk] =
            f2bf(acc[i][j][r]);
    }
  }
}

// ---------------- K5: out (128t x 128v tile) = attn_lat[h] @ v_b[h]^T ----------------
// grid (128, 4): x = h (stride-128 siblings -> same XCD). A-frags DIRECT from
// alat2 (fragment order -> coalesced); only B (fp32 vb) staged. __syncthreads.
__global__ __launch_bounds__(256) void out_gemm(const unsigned short* __restrict__ alat2,
                                                const float* __restrict__ vb,
                                                float* __restrict__ out) {
  const int h = blockIdx.x;
  const int tm = blockIdx.y * 128;  // token tile
  __shared__ __align__(16) unsigned short Bs[128 * 32];
  const int tid = threadIdx.x;
  const int lane = tid & 63, wave = tid >> 6;
  const int wm = (wave & 1) * 64, wn = (wave >> 1) * 64;
  const int l15 = lane & 15, quad = lane >> 4;
  const int r0 = tid >> 2, cg = tid & 3;
  const unsigned short* aab =
      alat2 + ((size_t)h * 8192 + tm + wm + l15) * 32 + quad * 8;
  const float* b0 = vb + ((size_t)h * 128 + r0) * 512 + cg * 8;
  const float* b1 = b0 + (size_t)64 * 512;
  floatx4 acc[4][4] = {};
  for (int ks = 0; ks < 16; ++ks) {  // contraction 512 = 16*32
    stage8_f32(b0 + ks * 32, &Bs[tid * 8]);
    stage8_f32(b1 + ks * 32, &Bs[2048 + tid * 8]);
    __syncthreads();
    bf16x8 af[4], bfr[4];
#pragma unroll
    for (int i = 0; i < 4; ++i)
      af[i] = *reinterpret_cast<const bf16x8*>(
          aab + (size_t)ks * 16384 + i * 512);
#pragma unroll
    for (int j = 0; j < 4; ++j)
      bfr[j] = *reinterpret_cast<const bf16x8*>(
          &Bs[(wn + j * 16 + l15) * 32 + quad * 8]);
#pragma unroll
    for (int i = 0; i < 4; ++i)
#pragma unroll
      for (int j = 0; j < 4; ++j)
        acc[i][j] =
            __builtin_amdgcn_mfma_f32_16x16x32_bf16(af[i], bfr[j], acc[i][j], 0, 0, 0);
    __syncthreads();
  }
#pragma unroll
  for (int i = 0; i < 4; ++i) {
    const int row = wm + i * 16 + quad * 4;  // token-local
#pragma unroll
    for (int j = 0; j < 4; ++j) {
      const int col = wn + j * 16 + l15;  // v
#pragma unroll
      for (int r = 0; r < 4; ++r) {
        const int t = tm + row + r;
        out[((size_t)t * 128 + h) * 128 + col] = acc[i][j][r];
      }
    }
  }
}

extern "C" void kernel_launch(void* const* d_in, const int* in_sizes, int n_in,
                              void* d_out, int out_size, void* d_ws, size_t ws_size,
                              hipStream_t stream) {
  const float* q = (const float*)d_in[0];         // (512,128,192)
  const float* kv = (const float*)d_in[1];        // (8192,576)
  const int* topk = (const int*)d_in[2];          // (512,512)
  const float* kb = (const float*)d_in[3];        // (128,512,128)
  const float* vb = (const float*)d_in[4];        // (128,128,512)
  float* out = (float*)d_out;                     // (512,128,128)

  char* ws = (char*)d_ws;
  unsigned short* kvb = (unsigned short*)ws;                        // 9,437,184 B
  unsigned short* qc2 = (unsigned short*)(ws + 9437184);            // 75,497,472 B
  unsigned short* P2 = (unsigned short*)(ws + 9437184 + 75497472);  // 67,108,864 B
  // P2 must NOT alias qc2 (scores_fused reads qc2 while writing P2).
  // alat2 reuses qc2 (dead after scores_fused). Total ws unchanged: 152 MB.
  unsigned short* alat2 = qc2;

  prep<<<dim3(20992), dim3(256), 0, stream>>>(kv, kvb, q, qc2);
  qlat_gemm<<<dim3(128, 16), dim3(256), 0, stream>>>(q, kb, qc2);
  scores_fused<<<dim3(512), dim3(1024), 0, stream>>>(qc2, kvb, topk, P2);
  attn_gemm<<<dim3(512), dim3(1024), 0, stream>>>(P2, kvb, topk, alat2);
  out_gemm<<<dim3(128, 4), dim3(256), 0, stream>>>(alat2, vb, out);
}